// Round 5
// baseline (3643.553 us; speedup 1.0000x reference)
//
#include <hip/hip_runtime.h>

#define N_CONS 100000
#define N_VAR  200000
#define N_TOT  (N_CONS + N_VAR)
#define N_EDGE 2000000
#define EMB 64

#define VSH 10
#define NBV 196   // ceil(200000/1024)
#define CAPV 12288
#define CSH 9
#define NBC 196   // ceil(100000/512)
#define CAPC 12288

// ---------------- bf16 helpers ----------------

__device__ __forceinline__ float b2f_lo(unsigned u) {
  union { unsigned i; float f; } c;
  c.i = u << 16;
  return c.f;
}
__device__ __forceinline__ float b2f_hi(unsigned u) {
  union { unsigned i; float f; } c;
  c.i = u & 0xFFFF0000u;
  return c.f;
}
__device__ __forceinline__ unsigned pack_bf2(float a, float b) {
  unsigned ua = __float_as_uint(a), ub = __float_as_uint(b);
  unsigned ra = (ua + 0x7FFFu + ((ua >> 16) & 1u)) >> 16;
  unsigned rb = (ub + 0x7FFFu + ((ub >> 16) & 1u)) >> 16;
  return ra | (rb << 16);
}

// ---------------- CSR build: bucketed counting sort ----------------

__global__ __launch_bounds__(256) void csr_init(int* __restrict__ gcurV,
                                                int* __restrict__ gcurC,
                                                int* __restrict__ off) {
  int t = threadIdx.x;
  if (t < NBV) gcurV[t] = t * CAPV;
  if (t < NBC) gcurC[t] = t * CAPC;
  if (t == 0) off[N_TOT] = 2 * N_EDGE;
}

__global__ __launch_bounds__(256) void bucket_scatter(
    const int* __restrict__ row, const int* __restrict__ col,
    int* __restrict__ gcurV, int* __restrict__ gcurC,
    int* __restrict__ pairV, int* __restrict__ pairC) {
  __shared__ int hV[NBV];
  __shared__ int hC[NBC];
  int tid = threadIdx.x;
  int chunk = (N_EDGE + gridDim.x - 1) / gridDim.x;
  int lo = blockIdx.x * chunk;
  int hi = min(N_EDGE, lo + chunk);
  for (int i = tid; i < NBV; i += 256) hV[i] = 0;
  for (int i = tid; i < NBC; i += 256) hC[i] = 0;
  __syncthreads();
  for (int e = lo + tid; e < hi; e += 256) {
    atomicAdd(&hV[col[e] >> VSH], 1);
    atomicAdd(&hC[row[e] >> CSH], 1);
  }
  __syncthreads();
  for (int i = tid; i < NBV; i += 256) {
    int c = hV[i];
    hV[i] = c ? atomicAdd(&gcurV[i], c) : 0;
  }
  for (int i = tid; i < NBC; i += 256) {
    int c = hC[i];
    hC[i] = c ? atomicAdd(&gcurC[i], c) : 0;
  }
  __syncthreads();
  for (int e = lo + tid; e < hi; e += 256) {
    int r = row[e], c = col[e];
    int p = atomicAdd(&hV[c >> VSH], 1);
    pairV[p] = (r << VSH) | (c & ((1 << VSH) - 1));
    int q = atomicAdd(&hC[r >> CSH], 1);
    pairC[q] = (c << CSH) | (r & ((1 << CSH) - 1));
  }
}

__global__ __launch_bounds__(256) void bucket_scan(const int* __restrict__ gcurV,
                                                   const int* __restrict__ gcurC,
                                                   int* __restrict__ ebaseV,
                                                   int* __restrict__ ebaseC) {
  __shared__ int s[256];
  int t = threadIdx.x;
  int v = (t < NBV) ? (gcurV[t] - t * CAPV) : 0;
  s[t] = v;
  __syncthreads();
  for (int d = 1; d < 256; d <<= 1) {
    int x = (t >= d) ? s[t - d] : 0;
    __syncthreads();
    s[t] += x;
    __syncthreads();
  }
  if (t < NBV) ebaseV[t] = s[t] - v;
  if (t == NBV - 1) ebaseV[NBV] = s[t];
  __syncthreads();
  int c = (t < NBC) ? (gcurC[t] - t * CAPC) : 0;
  s[t] = c;
  __syncthreads();
  for (int d = 1; d < 256; d <<= 1) {
    int x = (t >= d) ? s[t - d] : 0;
    __syncthreads();
    s[t] += x;
    __syncthreads();
  }
  if (t < NBC) ebaseC[t] = s[t] - c;
  if (t == NBC - 1) ebaseC[NBC] = s[t];
}

__global__ __launch_bounds__(256) void local_csr(
    const int* __restrict__ pairV, const int* __restrict__ pairC,
    const int* __restrict__ ebaseV, const int* __restrict__ ebaseC,
    int* __restrict__ off, int* __restrict__ adj) {
  __shared__ int cnt[1024];
  __shared__ int cur[1024];
  __shared__ int s[256];
  int tid = threadIdx.x;
  int b = blockIdx.x;
  const int* pairs;
  int m, obase, nn, sh;
  int* offp;
  if (b < NBV) {
    pairs = pairV + (size_t)b * CAPV;
    m = ebaseV[b + 1] - ebaseV[b];
    obase = ebaseV[b];
    nn = min(1024, N_VAR - (b << 10));
    sh = VSH;
    offp = off + (b << 10);
  } else {
    int bb = b - NBV;
    pairs = pairC + (size_t)bb * CAPC;
    m = ebaseC[bb + 1] - ebaseC[bb];
    obase = N_EDGE + ebaseC[bb];
    nn = min(512, N_CONS - (bb << 9));
    sh = CSH;
    offp = off + N_VAR + (bb << 9);
  }
  int mask = (1 << sh) - 1;
  for (int i = tid; i < 1024; i += 256) cnt[i] = 0;
  __syncthreads();
  for (int k = tid; k < m; k += 256) atomicAdd(&cnt[pairs[k] & mask], 1);
  __syncthreads();
  int i0 = tid * 4;
  int c0 = cnt[i0], c1 = cnt[i0 + 1], c2 = cnt[i0 + 2], c3 = cnt[i0 + 3];
  int sum = c0 + c1 + c2 + c3;
  s[tid] = sum;
  __syncthreads();
  for (int d = 1; d < 256; d <<= 1) {
    int x = (tid >= d) ? s[tid - d] : 0;
    __syncthreads();
    s[tid] += x;
    __syncthreads();
  }
  int run = obase + s[tid] - sum;
  int vals[4] = {c0, c1, c2, c3};
#pragma unroll
  for (int q = 0; q < 4; ++q) {
    int i = i0 + q;
    cur[i] = run;
    if (i < nn) offp[i] = run;
    run += vals[q];
  }
  __syncthreads();
  for (int k = tid; k < m; k += 256) {
    int pr = pairs[k];
    int p = atomicAdd(&cur[pr & mask], 1);
    adj[p] = pr >> sh;
  }
}

// ---------------- Embedding as tiled GEMM; writes fp32 + bf16 copies ----------------

template <int F>
__global__ __launch_bounds__(256) void embed_mm(
    const float* __restrict__ x, const float* __restrict__ shift,
    const float* __restrict__ scale, const float* __restrict__ W1,
    const float* __restrict__ b1, const float* __restrict__ W2,
    const float* __restrict__ b2, const float* __restrict__ bi,
    const float* __restrict__ bW, float* __restrict__ out,
    uint2* __restrict__ outbf, int n) {
  __shared__ float Xs[64 * F];
  __shared__ float W1s[F][64];
  __shared__ float Hs[64][68];
  __shared__ float W2s[64][64];
  __shared__ float b1s[64], b2s[64], bWs[64], bis[64];
  int t = threadIdx.x;
  int v0 = blockIdx.x * 64;
  for (int i = t; i < F * 64; i += 256) W1s[i / 64][i % 64] = W1[i] * scale[i / 64];
  for (int i = t; i < 64 * 64; i += 256) ((float*)W2s)[i] = W2[i];
  if (t < 64) {
    float acc = b1[t];
#pragma unroll
    for (int k = 0; k < F; ++k) acc += shift[k] * scale[k] * W1[k * 64 + t];
    b1s[t] = acc;
    b2s[t] = b2[t];
    bWs[t] = bW ? bW[t] : 0.f;
    bis[t] = (bi && v0 + t < n) ? bi[v0 + t] : 0.f;
  }
  int count = (min(n, v0 + 64) - v0) * F;
  for (int i = t; i < count; i += 256) Xs[i] = x[(size_t)v0 * F + i];
  __syncthreads();

  int jt = t & 15;
  int vt = t >> 4;
  float c[4][4] = {};
#pragma unroll
  for (int k = 0; k < F; ++k) {
    float w0 = W1s[k][jt * 4], w1 = W1s[k][jt * 4 + 1];
    float w2 = W1s[k][jt * 4 + 2], w3 = W1s[k][jt * 4 + 3];
#pragma unroll
    for (int i = 0; i < 4; ++i) {
      float xv = Xs[(vt * 4 + i) * F + k];
      c[i][0] += xv * w0;
      c[i][1] += xv * w1;
      c[i][2] += xv * w2;
      c[i][3] += xv * w3;
    }
  }
#pragma unroll
  for (int i = 0; i < 4; ++i)
#pragma unroll
    for (int q = 0; q < 4; ++q)
      Hs[vt * 4 + i][jt * 4 + q] = fmaxf(c[i][q] + b1s[jt * 4 + q], 0.f);
  __syncthreads();
  float d[4][4] = {};
#pragma unroll 4
  for (int k4 = 0; k4 < 16; ++k4) {
    float4 xv[4], wv[4];
#pragma unroll
    for (int i = 0; i < 4; ++i) xv[i] = *(const float4*)&Hs[vt * 4 + i][k4 * 4];
#pragma unroll
    for (int kk = 0; kk < 4; ++kk) wv[kk] = *(const float4*)&W2s[k4 * 4 + kk][jt * 4];
#pragma unroll
    for (int i = 0; i < 4; ++i) {
      d[i][0] += xv[i].x * wv[0].x + xv[i].y * wv[1].x + xv[i].z * wv[2].x + xv[i].w * wv[3].x;
      d[i][1] += xv[i].x * wv[0].y + xv[i].y * wv[1].y + xv[i].z * wv[2].y + xv[i].w * wv[3].y;
      d[i][2] += xv[i].x * wv[0].z + xv[i].y * wv[1].z + xv[i].z * wv[2].z + xv[i].w * wv[3].z;
      d[i][3] += xv[i].x * wv[0].w + xv[i].y * wv[1].w + xv[i].z * wv[2].w + xv[i].w * wv[3].w;
    }
  }
#pragma unroll
  for (int i = 0; i < 4; ++i) {
    int v = v0 + vt * 4 + i;
    if (v < n) {
      float bv = bis[vt * 4 + i];
      float4 o;
      o.x = fmaxf(d[i][0] + b2s[jt * 4 + 0], 0.f) + bv * bWs[jt * 4 + 0];
      o.y = fmaxf(d[i][1] + b2s[jt * 4 + 1], 0.f) + bv * bWs[jt * 4 + 1];
      o.z = fmaxf(d[i][2] + b2s[jt * 4 + 2], 0.f) + bv * bWs[jt * 4 + 2];
      o.w = fmaxf(d[i][3] + b2s[jt * 4 + 3], 0.f) + bv * bWs[jt * 4 + 3];
      *(float4*)&out[(size_t)v * 64 + jt * 4] = o;
      outbf[(size_t)v * 16 + jt] = make_uint2(pack_bf2(o.x, o.y), pack_bf2(o.z, o.w));
    }
  }
}

// ---------------- Fused SAGE: bf16 gather-mean into LDS, K-split dual GEMM ----------------
// out = relu(mean(srcbf[neigh]) @ Wl + bl + dstx @ Wr), 64-node tile per block

template <int OUTBF>
__global__ __launch_bounds__(256) void sage_fused(
    const uint2* __restrict__ srcbf, const float* __restrict__ dstx,
    const int* __restrict__ off, const int* __restrict__ adj,
    const float* __restrict__ Wl, const float* __restrict__ bl,
    const float* __restrict__ Wr, float* __restrict__ outf,
    uint2* __restrict__ outbf, int n) {
  __shared__ float Hs[64][68];
  __shared__ float Ws[32][64];
  __shared__ float bls[64];
  int t = threadIdx.x;
  int v0 = blockIdx.x * 64;
  if (t < 64) bls[t] = bl[t];

  int jt = t & 15;
  int vt = t >> 4;
  auto stage = [&](const float* Wg, int kbase) {
#pragma unroll
    for (int r2 = 0; r2 < 2; ++r2) {
      int idx = t + 256 * r2;
      int rowi = idx >> 4, c4 = idx & 15;
      *(float4*)&Ws[rowi][c4 * 4] = ((const float4*)Wg)[(size_t)(kbase + rowi) * 16 + c4];
    }
  };

  stage(Wl, 0);  // overlap first W chunk with gather

  // Phase A: gather-mean (bf16 rows, 16 lanes/node, uint2/lane)
  int lane = t & 15;
  int g = t >> 4;
#pragma unroll
  for (int grp = 0; grp < 4; ++grp) {
    int r = grp * 16 + g;
    int v = v0 + r;
    float ax = 0.f, ay = 0.f, az = 0.f, aw = 0.f;
    if (v < n) {
      int s0 = off[v], s1 = off[v + 1];
      int i = s0;
      for (; i + 2 <= s1; i += 2) {
        uint2 a = srcbf[(size_t)adj[i] * 16 + lane];
        uint2 b = srcbf[(size_t)adj[i + 1] * 16 + lane];
        ax += b2f_lo(a.x) + b2f_lo(b.x);
        ay += b2f_hi(a.x) + b2f_hi(b.x);
        az += b2f_lo(a.y) + b2f_lo(b.y);
        aw += b2f_hi(a.y) + b2f_hi(b.y);
      }
      if (i < s1) {
        uint2 a = srcbf[(size_t)adj[i] * 16 + lane];
        ax += b2f_lo(a.x);
        ay += b2f_hi(a.x);
        az += b2f_lo(a.y);
        aw += b2f_hi(a.y);
      }
      int deg = s1 - s0;
      float inv = (deg > 0) ? 1.f / (float)deg : 0.f;
      ax *= inv;
      ay *= inv;
      az *= inv;
      aw *= inv;
    }
    *(float4*)&Hs[r][lane * 4] = make_float4(ax, ay, az, aw);
  }

  float c[4][4] = {};
  bool valid[4];
#pragma unroll
  for (int i = 0; i < 4; ++i) valid[i] = (v0 + vt * 4 + i) < n;

  auto fma4 = [&](const float4 (&xv)[4], const float4 (&wv)[4]) {
#pragma unroll
    for (int i = 0; i < 4; ++i) {
      c[i][0] += xv[i].x * wv[0].x + xv[i].y * wv[1].x + xv[i].z * wv[2].x + xv[i].w * wv[3].x;
      c[i][1] += xv[i].x * wv[0].y + xv[i].y * wv[1].y + xv[i].z * wv[2].y + xv[i].w * wv[3].y;
      c[i][2] += xv[i].x * wv[0].z + xv[i].y * wv[1].z + xv[i].z * wv[2].z + xv[i].w * wv[3].z;
      c[i][3] += xv[i].x * wv[0].w + xv[i].y * wv[1].w + xv[i].z * wv[2].w + xv[i].w * wv[3].w;
    }
  };
  auto comp_h = [&](int kbase) {
#pragma unroll
    for (int k4 = 0; k4 < 8; ++k4) {
      float4 xv[4], wv[4];
#pragma unroll
      for (int i = 0; i < 4; ++i) xv[i] = *(const float4*)&Hs[vt * 4 + i][kbase + k4 * 4];
#pragma unroll
      for (int kk = 0; kk < 4; ++kk) wv[kk] = *(const float4*)&Ws[k4 * 4 + kk][jt * 4];
      fma4(xv, wv);
    }
  };
  auto comp_g = [&](int kbase) {
    const float4* dst4 = (const float4*)dstx;
#pragma unroll
    for (int k4 = 0; k4 < 8; ++k4) {
      float4 xv[4], wv[4];
#pragma unroll
      for (int i = 0; i < 4; ++i)
        xv[i] = valid[i] ? dst4[(size_t)(v0 + vt * 4 + i) * 16 + (kbase / 4 + k4)]
                         : make_float4(0.f, 0.f, 0.f, 0.f);
#pragma unroll
      for (int kk = 0; kk < 4; ++kk) wv[kk] = *(const float4*)&Ws[k4 * 4 + kk][jt * 4];
      fma4(xv, wv);
    }
  };

  __syncthreads();  // Hs + Ws(Wl,0) ready
  comp_h(0);
  __syncthreads();
  stage(Wl, 32);
  __syncthreads();
  comp_h(32);
  __syncthreads();
  stage(Wr, 0);
  __syncthreads();
  comp_g(0);
  __syncthreads();
  stage(Wr, 32);
  __syncthreads();
  comp_g(32);

#pragma unroll
  for (int i = 0; i < 4; ++i) {
    int v = v0 + vt * 4 + i;
    if (v < n) {
      float4 o;
      o.x = fmaxf(c[i][0] + bls[jt * 4 + 0], 0.f);
      o.y = fmaxf(c[i][1] + bls[jt * 4 + 1], 0.f);
      o.z = fmaxf(c[i][2] + bls[jt * 4 + 2], 0.f);
      o.w = fmaxf(c[i][3] + bls[jt * 4 + 3], 0.f);
      if (OUTBF) {
        outbf[(size_t)v * 16 + jt] = make_uint2(pack_bf2(o.x, o.y), pack_bf2(o.z, o.w));
      } else {
        *(float4*)&outf[(size_t)v * 64 + jt * 4] = o;
      }
    }
  }
}

// ---------------- host ----------------

extern "C" void kernel_launch(void* const* d_in, const int* in_sizes, int n_in,
                              void* d_out, int out_size, void* d_ws, size_t ws_size,
                              hipStream_t stream) {
  const float* cons_x = (const float*)d_in[0];
  const float* var_x  = (const float*)d_in[1];
  const int*   eidx   = (const int*)d_in[2];
  const float* bi     = (const float*)d_in[4];
  const float* c_sh   = (const float*)d_in[5];
  const float* c_sc   = (const float*)d_in[6];
  const float* v_sh   = (const float*)d_in[7];
  const float* v_sc   = (const float*)d_in[8];
  const float* cW1 = (const float*)d_in[11];
  const float* cb1 = (const float*)d_in[12];
  const float* cW2 = (const float*)d_in[13];
  const float* cb2 = (const float*)d_in[14];
  const float* vW1 = (const float*)d_in[15];
  const float* vb1 = (const float*)d_in[16];
  const float* vW2 = (const float*)d_in[17];
  const float* vb2 = (const float*)d_in[18];
  const float* bW  = (const float*)d_in[19];
  const float* Wl_cv = (const float*)d_in[20];
  const float* bl_cv = (const float*)d_in[21];
  const float* Wr_cv = (const float*)d_in[22];
  const float* Wl_vc = (const float*)d_in[23];
  const float* bl_vc = (const float*)d_in[24];
  const float* Wr_vc = (const float*)d_in[25];

  const int* row = eidx;           // [E] constraint index per edge
  const int* col = eidx + N_EDGE;  // [E] variable index per edge

  char* ws = (char*)d_ws;
  size_t o = 0;
  auto alloc = [&](size_t bytes) {
    char* p = ws + o;
    o = (o + bytes + 255) & ~(size_t)255;
    return p;
  };
  int* off    = (int*)alloc((N_TOT + 1) * sizeof(int));
  int* adj    = (int*)alloc((size_t)2 * N_EDGE * sizeof(int));
  int* pairV  = (int*)alloc((size_t)NBV * CAPV * sizeof(int));
  int* pairC  = (int*)alloc((size_t)NBC * CAPC * sizeof(int));
  int* gcurV  = (int*)alloc(256 * sizeof(int));
  int* gcurC  = (int*)alloc(256 * sizeof(int));
  int* ebaseV = (int*)alloc(256 * sizeof(int));
  int* ebaseC = (int*)alloc(256 * sizeof(int));
  float* consE   = (float*)alloc((size_t)N_CONS * EMB * sizeof(float));
  float* varE    = (float*)alloc((size_t)N_VAR * EMB * sizeof(float));
  uint2* consEbf = (uint2*)alloc((size_t)N_CONS * EMB * 2);
  uint2* varEbf  = (uint2*)alloc((size_t)N_VAR * EMB * 2);
  uint2* cons1bf = (uint2*)alloc((size_t)N_CONS * EMB * 2);
  float* var1    = (float*)d_out;

  csr_init<<<1, 256, 0, stream>>>(gcurV, gcurC, off);
  bucket_scatter<<<512, 256, 0, stream>>>(row, col, gcurV, gcurC, pairV, pairC);
  bucket_scan<<<1, 256, 0, stream>>>(gcurV, gcurC, ebaseV, ebaseC);
  local_csr<<<NBV + NBC, 256, 0, stream>>>(pairV, pairC, ebaseV, ebaseC, off, adj);

  embed_mm<5><<<(N_CONS + 63) / 64, 256, 0, stream>>>(
      cons_x, c_sh, c_sc, cW1, cb1, cW2, cb2, nullptr, nullptr, consE, consEbf,
      N_CONS);
  embed_mm<19><<<(N_VAR + 63) / 64, 256, 0, stream>>>(
      var_x, v_sh, v_sc, vW1, vb1, vW2, vb2, bi, bW, varE, varEbf, N_VAR);

  // layer 0, var side: d_out = relu(mean_cons @ Wl_cv + bl + varE @ Wr_cv)
  sage_fused<0><<<(N_VAR + 63) / 64, 256, 0, stream>>>(
      consEbf, varE, off, adj, Wl_cv, bl_cv, Wr_cv, var1, nullptr, N_VAR);
  // layer 0, cons side -> bf16 only (gather source of layer 1)
  sage_fused<1><<<(N_CONS + 63) / 64, 256, 0, stream>>>(
      varEbf, consE, off + N_VAR, adj, Wl_vc, bl_vc, Wr_vc, nullptr, cons1bf,
      N_CONS);
  // layer 1, var side only (in-place d_out as dstx and out)
  sage_fused<0><<<(N_VAR + 63) / 64, 256, 0, stream>>>(
      cons1bf, var1, off, adj, Wl_cv + 4096, bl_cv + 64, Wr_cv + 4096, var1,
      nullptr, N_VAR);
}

// Round 6
// 519.397 us; speedup vs baseline: 7.0150x; 7.0150x over previous
//
#include <hip/hip_runtime.h>

#define N_CONS 100000
#define N_VAR  200000
#define N_TOT  (N_CONS + N_VAR)
#define N_EDGE 2000000
#define EMB 64

#define VSH 10
#define NBV 196   // ceil(200000/1024)
#define CAPV 12288
#define CSH 9
#define NBC 196   // ceil(100000/512)
#define CAPC 12288

// ---------------- bf16 helpers ----------------

__device__ __forceinline__ float b2f_lo(unsigned u) {
  union { unsigned i; float f; } c;
  c.i = u << 16;
  return c.f;
}
__device__ __forceinline__ float b2f_hi(unsigned u) {
  union { unsigned i; float f; } c;
  c.i = u & 0xFFFF0000u;
  return c.f;
}
__device__ __forceinline__ unsigned pack_bf2(float a, float b) {
  unsigned ua = __float_as_uint(a), ub = __float_as_uint(b);
  unsigned ra = (ua + 0x7FFFu + ((ua >> 16) & 1u)) >> 16;
  unsigned rb = (ub + 0x7FFFu + ((ub >> 16) & 1u)) >> 16;
  return ra | (rb << 16);
}

// ---------------- CSR build: bucketed counting sort ----------------

__global__ __launch_bounds__(256) void csr_init(int* __restrict__ gcurV,
                                                int* __restrict__ gcurC,
                                                int* __restrict__ off) {
  int t = threadIdx.x;
  if (t < NBV) gcurV[t] = t * CAPV;
  if (t < NBC) gcurC[t] = t * CAPC;
  if (t == 0) off[N_TOT] = 2 * N_EDGE;
}

__global__ __launch_bounds__(256) void bucket_scatter(
    const int* __restrict__ row, const int* __restrict__ col,
    int* __restrict__ gcurV, int* __restrict__ gcurC,
    int* __restrict__ pairV, int* __restrict__ pairC) {
  __shared__ int hV[NBV];
  __shared__ int hC[NBC];
  int tid = threadIdx.x;
  int chunk = (N_EDGE + gridDim.x - 1) / gridDim.x;
  int lo = blockIdx.x * chunk;
  int hi = min(N_EDGE, lo + chunk);
  for (int i = tid; i < NBV; i += 256) hV[i] = 0;
  for (int i = tid; i < NBC; i += 256) hC[i] = 0;
  __syncthreads();
  for (int e = lo + tid; e < hi; e += 256) {
    atomicAdd(&hV[col[e] >> VSH], 1);
    atomicAdd(&hC[row[e] >> CSH], 1);
  }
  __syncthreads();
  for (int i = tid; i < NBV; i += 256) {
    int c = hV[i];
    hV[i] = c ? atomicAdd(&gcurV[i], c) : 0;
  }
  for (int i = tid; i < NBC; i += 256) {
    int c = hC[i];
    hC[i] = c ? atomicAdd(&gcurC[i], c) : 0;
  }
  __syncthreads();
  for (int e = lo + tid; e < hi; e += 256) {
    int r = row[e], c = col[e];
    int p = atomicAdd(&hV[c >> VSH], 1);
    pairV[p] = (r << VSH) | (c & ((1 << VSH) - 1));
    int q = atomicAdd(&hC[r >> CSH], 1);
    pairC[q] = (c << CSH) | (r & ((1 << CSH) - 1));
  }
}

__global__ __launch_bounds__(256) void bucket_scan(const int* __restrict__ gcurV,
                                                   const int* __restrict__ gcurC,
                                                   int* __restrict__ ebaseV,
                                                   int* __restrict__ ebaseC) {
  __shared__ int s[256];
  int t = threadIdx.x;
  int v = (t < NBV) ? (gcurV[t] - t * CAPV) : 0;
  s[t] = v;
  __syncthreads();
  for (int d = 1; d < 256; d <<= 1) {
    int x = (t >= d) ? s[t - d] : 0;
    __syncthreads();
    s[t] += x;
    __syncthreads();
  }
  if (t < NBV) ebaseV[t] = s[t] - v;
  if (t == NBV - 1) ebaseV[NBV] = s[t];
  __syncthreads();
  int c = (t < NBC) ? (gcurC[t] - t * CAPC) : 0;
  s[t] = c;
  __syncthreads();
  for (int d = 1; d < 512; d <<= 1) {
    int x = (t >= d) ? s[t - d] : 0;
    __syncthreads();
    s[t] += x;
    __syncthreads();
  }
  if (t < NBC) ebaseC[t] = s[t] - c;
  if (t == NBC - 1) ebaseC[NBC] = s[t];
}

__global__ __launch_bounds__(256) void local_csr(
    const int* __restrict__ pairV, const int* __restrict__ pairC,
    const int* __restrict__ ebaseV, const int* __restrict__ ebaseC,
    int* __restrict__ off, int* __restrict__ adj) {
  __shared__ int cnt[1024];
  __shared__ int cur[1024];
  __shared__ int s[256];
  int tid = threadIdx.x;
  int b = blockIdx.x;
  const int* pairs;
  int m, obase, nn, sh;
  int* offp;
  if (b < NBV) {
    pairs = pairV + (size_t)b * CAPV;
    m = ebaseV[b + 1] - ebaseV[b];
    obase = ebaseV[b];
    nn = min(1024, N_VAR - (b << 10));
    sh = VSH;
    offp = off + (b << 10);
  } else {
    int bb = b - NBV;
    pairs = pairC + (size_t)bb * CAPC;
    m = ebaseC[bb + 1] - ebaseC[bb];
    obase = N_EDGE + ebaseC[bb];
    nn = min(512, N_CONS - (bb << 9));
    sh = CSH;
    offp = off + N_VAR + (bb << 9);
  }
  int mask = (1 << sh) - 1;
  for (int i = tid; i < 1024; i += 256) cnt[i] = 0;
  __syncthreads();
  for (int k = tid; k < m; k += 256) atomicAdd(&cnt[pairs[k] & mask], 1);
  __syncthreads();
  int i0 = tid * 4;
  int c0 = cnt[i0], c1 = cnt[i0 + 1], c2 = cnt[i0 + 2], c3 = cnt[i0 + 3];
  int sum = c0 + c1 + c2 + c3;
  s[tid] = sum;
  __syncthreads();
  for (int d = 1; d < 256; d <<= 1) {
    int x = (tid >= d) ? s[tid - d] : 0;
    __syncthreads();
    s[tid] += x;
    __syncthreads();
  }
  int run = obase + s[tid] - sum;
  int vals[4] = {c0, c1, c2, c3};
#pragma unroll
  for (int q = 0; q < 4; ++q) {
    int i = i0 + q;
    cur[i] = run;
    if (i < nn) offp[i] = run;
    run += vals[q];
  }
  __syncthreads();
  for (int k = tid; k < m; k += 256) {
    int pr = pairs[k];
    int p = atomicAdd(&cur[pr & mask], 1);
    adj[p] = pr >> sh;
  }
}

// ---------------- Embedding as tiled GEMM; writes fp32 + bf16 copies ----------------

template <int F>
__global__ __launch_bounds__(256) void embed_mm(
    const float* __restrict__ x, const float* __restrict__ shift,
    const float* __restrict__ scale, const float* __restrict__ W1,
    const float* __restrict__ b1, const float* __restrict__ W2,
    const float* __restrict__ b2, const float* __restrict__ bi,
    const float* __restrict__ bW, float* __restrict__ out,
    uint2* __restrict__ outbf, int n) {
  __shared__ float Xs[64 * F];
  __shared__ float W1s[F][64];
  __shared__ float Hs[64][68];
  __shared__ float W2s[64][64];
  __shared__ float b1s[64], b2s[64], bWs[64], bis[64];
  int t = threadIdx.x;
  int v0 = blockIdx.x * 64;
  for (int i = t; i < F * 64; i += 256) W1s[i / 64][i % 64] = W1[i] * scale[i / 64];
  for (int i = t; i < 64 * 64; i += 256) ((float*)W2s)[i] = W2[i];
  if (t < 64) {
    float acc = b1[t];
#pragma unroll
    for (int k = 0; k < F; ++k) acc += shift[k] * scale[k] * W1[k * 64 + t];
    b1s[t] = acc;
    b2s[t] = b2[t];
    bWs[t] = bW ? bW[t] : 0.f;
    bis[t] = (bi && v0 + t < n) ? bi[v0 + t] : 0.f;
  }
  int count = (min(n, v0 + 64) - v0) * F;
  for (int i = t; i < count; i += 256) Xs[i] = x[(size_t)v0 * F + i];
  __syncthreads();

  int jt = t & 15;
  int vt = t >> 4;
  float c[4][4] = {};
#pragma unroll
  for (int k = 0; k < F; ++k) {
    float w0 = W1s[k][jt * 4], w1 = W1s[k][jt * 4 + 1];
    float w2 = W1s[k][jt * 4 + 2], w3 = W1s[k][jt * 4 + 3];
#pragma unroll
    for (int i = 0; i < 4; ++i) {
      float xv = Xs[(vt * 4 + i) * F + k];
      c[i][0] += xv * w0;
      c[i][1] += xv * w1;
      c[i][2] += xv * w2;
      c[i][3] += xv * w3;
    }
  }
#pragma unroll
  for (int i = 0; i < 4; ++i)
#pragma unroll
    for (int q = 0; q < 4; ++q)
      Hs[vt * 4 + i][jt * 4 + q] = fmaxf(c[i][q] + b1s[jt * 4 + q], 0.f);
  __syncthreads();
  float d[4][4] = {};
#pragma unroll 4
  for (int k4 = 0; k4 < 16; ++k4) {
    float4 xv[4], wv[4];
#pragma unroll
    for (int i = 0; i < 4; ++i) xv[i] = *(const float4*)&Hs[vt * 4 + i][k4 * 4];
#pragma unroll
    for (int kk = 0; kk < 4; ++kk) wv[kk] = *(const float4*)&W2s[k4 * 4 + kk][jt * 4];
#pragma unroll
    for (int i = 0; i < 4; ++i) {
      d[i][0] += xv[i].x * wv[0].x + xv[i].y * wv[1].x + xv[i].z * wv[2].x + xv[i].w * wv[3].x;
      d[i][1] += xv[i].x * wv[0].y + xv[i].y * wv[1].y + xv[i].z * wv[2].y + xv[i].w * wv[3].y;
      d[i][2] += xv[i].x * wv[0].z + xv[i].y * wv[1].z + xv[i].z * wv[2].z + xv[i].w * wv[3].z;
      d[i][3] += xv[i].x * wv[0].w + xv[i].y * wv[1].w + xv[i].z * wv[2].w + xv[i].w * wv[3].w;
    }
  }
#pragma unroll
  for (int i = 0; i < 4; ++i) {
    int v = v0 + vt * 4 + i;
    if (v < n) {
      float bv = bis[vt * 4 + i];
      float4 o;
      o.x = fmaxf(d[i][0] + b2s[jt * 4 + 0], 0.f) + bv * bWs[jt * 4 + 0];
      o.y = fmaxf(d[i][1] + b2s[jt * 4 + 1], 0.f) + bv * bWs[jt * 4 + 1];
      o.z = fmaxf(d[i][2] + b2s[jt * 4 + 2], 0.f) + bv * bWs[jt * 4 + 2];
      o.w = fmaxf(d[i][3] + b2s[jt * 4 + 3], 0.f) + bv * bWs[jt * 4 + 3];
      *(float4*)&out[(size_t)v * 64 + jt * 4] = o;
      outbf[(size_t)v * 16 + jt] = make_uint2(pack_bf2(o.x, o.y), pack_bf2(o.z, o.w));
    }
  }
}

// ---------------- Fused SAGE (round-4 structure, bf16 gather) ----------------
// out = relu(mean(srcbf[neigh]) @ Wl + bl + dstx @ Wr), 64-node tile per block

template <int OUTBF>
__global__ __launch_bounds__(256) void sage_fused(
    const uint2* __restrict__ srcbf, const float* __restrict__ dstx,
    const int* __restrict__ off, const int* __restrict__ adj,
    const float* __restrict__ Wl, const float* __restrict__ bl,
    const float* __restrict__ Wr, float* __restrict__ outf,
    uint2* __restrict__ outbf, int n) {
  __shared__ float Hs[64][68];
  __shared__ float Ws[64][64];
  __shared__ float bls[64];
  int t = threadIdx.x;
  int v0 = blockIdx.x * 64;
  if (t < 64) bls[t] = bl[t];
  for (int i = t; i < 1024; i += 256) ((float4*)Ws)[i] = ((const float4*)Wl)[i];

  // Phase A: gather-mean into Hs (bf16 rows, 16 lanes/node, uint2/lane, unroll-2)
  int lane = t & 15;
  int g = t >> 4;
#pragma unroll
  for (int grp = 0; grp < 4; ++grp) {
    int r = grp * 16 + g;
    int v = v0 + r;
    float ax = 0.f, ay = 0.f, az = 0.f, aw = 0.f;
    if (v < n) {
      int s0 = off[v], s1 = off[v + 1];
      int i = s0;
      for (; i + 2 <= s1; i += 2) {
        uint2 a = srcbf[(size_t)adj[i] * 16 + lane];
        uint2 b = srcbf[(size_t)adj[i + 1] * 16 + lane];
        ax += b2f_lo(a.x) + b2f_lo(b.x);
        ay += b2f_hi(a.x) + b2f_hi(b.x);
        az += b2f_lo(a.y) + b2f_lo(b.y);
        aw += b2f_hi(a.y) + b2f_hi(b.y);
      }
      if (i < s1) {
        uint2 a = srcbf[(size_t)adj[i] * 16 + lane];
        ax += b2f_lo(a.x);
        ay += b2f_hi(a.x);
        az += b2f_lo(a.y);
        aw += b2f_hi(a.y);
      }
      int deg = s1 - s0;
      float inv = (deg > 0) ? 1.f / (float)deg : 0.f;
      ax *= inv;
      ay *= inv;
      az *= inv;
      aw *= inv;
    }
    *(float4*)&Hs[r][lane * 4] = make_float4(ax, ay, az, aw);
  }
  __syncthreads();

  int jt = t & 15;
  int vt = t >> 4;
  float c[4][4] = {};
  auto compute = [&]() {
#pragma unroll 4
    for (int k4 = 0; k4 < 16; ++k4) {
      float4 xv[4], wv[4];
#pragma unroll
      for (int i = 0; i < 4; ++i) xv[i] = *(const float4*)&Hs[vt * 4 + i][k4 * 4];
#pragma unroll
      for (int kk = 0; kk < 4; ++kk) wv[kk] = *(const float4*)&Ws[k4 * 4 + kk][jt * 4];
#pragma unroll
      for (int i = 0; i < 4; ++i) {
        c[i][0] += xv[i].x * wv[0].x + xv[i].y * wv[1].x + xv[i].z * wv[2].x + xv[i].w * wv[3].x;
        c[i][1] += xv[i].x * wv[0].y + xv[i].y * wv[1].y + xv[i].z * wv[2].y + xv[i].w * wv[3].y;
        c[i][2] += xv[i].x * wv[0].z + xv[i].y * wv[1].z + xv[i].z * wv[2].z + xv[i].w * wv[3].z;
        c[i][3] += xv[i].x * wv[0].w + xv[i].y * wv[1].w + xv[i].z * wv[2].w + xv[i].w * wv[3].w;
      }
    }
  };
  compute();  // mean @ Wl
  __syncthreads();
  // stage dstx tile + Wr
#pragma unroll
  for (int r = 0; r < 4; ++r) {
    int idx = t + 256 * r;
    int rowi = idx >> 4, f4 = idx & 15;
    int v = v0 + rowi;
    float4 val = (v < n) ? ((const float4*)dstx)[(size_t)v * 16 + f4]
                         : make_float4(0.f, 0.f, 0.f, 0.f);
    *(float4*)&Hs[rowi][f4 * 4] = val;
    ((float4*)Ws)[idx] = ((const float4*)Wr)[idx];
  }
  __syncthreads();
  compute();  // += dstx @ Wr

#pragma unroll
  for (int i = 0; i < 4; ++i) {
    int v = v0 + vt * 4 + i;
    if (v < n) {
      float4 o;
      o.x = fmaxf(c[i][0] + bls[jt * 4 + 0], 0.f);
      o.y = fmaxf(c[i][1] + bls[jt * 4 + 1], 0.f);
      o.z = fmaxf(c[i][2] + bls[jt * 4 + 2], 0.f);
      o.w = fmaxf(c[i][3] + bls[jt * 4 + 3], 0.f);
      if (OUTBF) {
        outbf[(size_t)v * 16 + jt] = make_uint2(pack_bf2(o.x, o.y), pack_bf2(o.z, o.w));
      } else {
        *(float4*)&outf[(size_t)v * 64 + jt * 4] = o;
      }
    }
  }
}

// ---------------- host ----------------

extern "C" void kernel_launch(void* const* d_in, const int* in_sizes, int n_in,
                              void* d_out, int out_size, void* d_ws, size_t ws_size,
                              hipStream_t stream) {
  const float* cons_x = (const float*)d_in[0];
  const float* var_x  = (const float*)d_in[1];
  const int*   eidx   = (const int*)d_in[2];
  const float* bi     = (const float*)d_in[4];
  const float* c_sh   = (const float*)d_in[5];
  const float* c_sc   = (const float*)d_in[6];
  const float* v_sh   = (const float*)d_in[7];
  const float* v_sc   = (const float*)d_in[8];
  const float* cW1 = (const float*)d_in[11];
  const float* cb1 = (const float*)d_in[12];
  const float* cW2 = (const float*)d_in[13];
  const float* cb2 = (const float*)d_in[14];
  const float* vW1 = (const float*)d_in[15];
  const float* vb1 = (const float*)d_in[16];
  const float* vW2 = (const float*)d_in[17];
  const float* vb2 = (const float*)d_in[18];
  const float* bW  = (const float*)d_in[19];
  const float* Wl_cv = (const float*)d_in[20];
  const float* bl_cv = (const float*)d_in[21];
  const float* Wr_cv = (const float*)d_in[22];
  const float* Wl_vc = (const float*)d_in[23];
  const float* bl_vc = (const float*)d_in[24];
  const float* Wr_vc = (const float*)d_in[25];

  const int* row = eidx;           // [E] constraint index per edge
  const int* col = eidx + N_EDGE;  // [E] variable index per edge

  char* ws = (char*)d_ws;
  size_t o = 0;
  auto alloc = [&](size_t bytes) {
    char* p = ws + o;
    o = (o + bytes + 255) & ~(size_t)255;
    return p;
  };
  int* off    = (int*)alloc((N_TOT + 1) * sizeof(int));
  int* adj    = (int*)alloc((size_t)2 * N_EDGE * sizeof(int));
  int* pairV  = (int*)alloc((size_t)NBV * CAPV * sizeof(int));
  int* pairC  = (int*)alloc((size_t)NBC * CAPC * sizeof(int));
  int* gcurV  = (int*)alloc(256 * sizeof(int));
  int* gcurC  = (int*)alloc(256 * sizeof(int));
  int* ebaseV = (int*)alloc(256 * sizeof(int));
  int* ebaseC = (int*)alloc(256 * sizeof(int));
  float* consE   = (float*)alloc((size_t)N_CONS * EMB * sizeof(float));
  float* varE    = (float*)alloc((size_t)N_VAR * EMB * sizeof(float));
  uint2* consEbf = (uint2*)alloc((size_t)N_CONS * EMB * 2);
  uint2* varEbf  = (uint2*)alloc((size_t)N_VAR * EMB * 2);
  uint2* cons1bf = (uint2*)alloc((size_t)N_CONS * EMB * 2);
  float* var1    = (float*)d_out;

  csr_init<<<1, 256, 0, stream>>>(gcurV, gcurC, off);
  bucket_scatter<<<512, 256, 0, stream>>>(row, col, gcurV, gcurC, pairV, pairC);
  bucket_scan<<<1, 256, 0, stream>>>(gcurV, gcurC, ebaseV, ebaseC);
  local_csr<<<NBV + NBC, 256, 0, stream>>>(pairV, pairC, ebaseV, ebaseC, off, adj);

  embed_mm<5><<<(N_CONS + 63) / 64, 256, 0, stream>>>(
      cons_x, c_sh, c_sc, cW1, cb1, cW2, cb2, nullptr, nullptr, consE, consEbf,
      N_CONS);
  embed_mm<19><<<(N_VAR + 63) / 64, 256, 0, stream>>>(
      var_x, v_sh, v_sc, vW1, vb1, vW2, vb2, bi, bW, varE, varEbf, N_VAR);

  // layer 0, var side: d_out = relu(mean_cons @ Wl_cv + bl + varE @ Wr_cv)
  sage_fused<0><<<(N_VAR + 63) / 64, 256, 0, stream>>>(
      consEbf, varE, off, adj, Wl_cv, bl_cv, Wr_cv, var1, nullptr, N_VAR);
  // layer 0, cons side -> bf16 only (gather source of layer 1)
  sage_fused<1><<<(N_CONS + 63) / 64, 256, 0, stream>>>(
      varEbf, consE, off + N_VAR, adj, Wl_vc, bl_vc, Wr_vc, nullptr, cons1bf,
      N_CONS);
  // layer 1, var side only (in-place d_out as dstx and out)
  sage_fused<0><<<(N_VAR + 63) / 64, 256, 0, stream>>>(
      cons1bf, var1, off, adj, Wl_cv + 4096, bl_cv + 64, Wr_cv + 4096, var1,
      nullptr, N_VAR);
}

// Round 7
// 451.532 us; speedup vs baseline: 8.0693x; 1.1503x over previous
//
#include <hip/hip_runtime.h>

#define N_CONS 100000
#define N_VAR  200000
#define N_TOT  (N_CONS + N_VAR)
#define N_EDGE 2000000
#define EMB 64

#define VSH 10
#define NBV 196   // ceil(200000/1024)
#define CAPV 12288
#define CSH 9
#define NBC 196   // ceil(100000/512)
#define CAPC 12288

// ---------------- bf16 helpers ----------------

__device__ __forceinline__ float b2f_lo(unsigned u) {
  union { unsigned i; float f; } c;
  c.i = u << 16;
  return c.f;
}
__device__ __forceinline__ float b2f_hi(unsigned u) {
  union { unsigned i; float f; } c;
  c.i = u & 0xFFFF0000u;
  return c.f;
}
__device__ __forceinline__ unsigned pack_bf2(float a, float b) {
  unsigned ua = __float_as_uint(a), ub = __float_as_uint(b);
  unsigned ra = (ua + 0x7FFFu + ((ua >> 16) & 1u)) >> 16;
  unsigned rb = (ub + 0x7FFFu + ((ub >> 16) & 1u)) >> 16;
  return ra | (rb << 16);
}

// ---------------- CSR build: bucketed counting sort ----------------

__global__ __launch_bounds__(256) void csr_init(int* __restrict__ gcurV,
                                                int* __restrict__ gcurC,
                                                int* __restrict__ off) {
  int t = threadIdx.x;
  if (t < NBV) gcurV[t] = t * CAPV;
  if (t < NBC) gcurC[t] = t * CAPC;
  if (t == 0) off[N_TOT] = 2 * N_EDGE;
}

__global__ __launch_bounds__(256) void bucket_scatter(
    const int* __restrict__ row, const int* __restrict__ col,
    int* __restrict__ gcurV, int* __restrict__ gcurC,
    int* __restrict__ pairV, int* __restrict__ pairC) {
  __shared__ int hV[NBV];
  __shared__ int hC[NBC];
  int tid = threadIdx.x;
  int chunk = (N_EDGE + gridDim.x - 1) / gridDim.x;
  int lo = blockIdx.x * chunk;
  int hi = min(N_EDGE, lo + chunk);
  for (int i = tid; i < NBV; i += 256) hV[i] = 0;
  for (int i = tid; i < NBC; i += 256) hC[i] = 0;
  __syncthreads();
  for (int e = lo + tid; e < hi; e += 256) {
    atomicAdd(&hV[col[e] >> VSH], 1);
    atomicAdd(&hC[row[e] >> CSH], 1);
  }
  __syncthreads();
  for (int i = tid; i < NBV; i += 256) {
    int c = hV[i];
    hV[i] = c ? atomicAdd(&gcurV[i], c) : 0;
  }
  for (int i = tid; i < NBC; i += 256) {
    int c = hC[i];
    hC[i] = c ? atomicAdd(&gcurC[i], c) : 0;
  }
  __syncthreads();
  for (int e = lo + tid; e < hi; e += 256) {
    int r = row[e], c = col[e];
    int p = atomicAdd(&hV[c >> VSH], 1);
    pairV[p] = (r << VSH) | (c & ((1 << VSH) - 1));
    int q = atomicAdd(&hC[r >> CSH], 1);
    pairC[q] = (c << CSH) | (r & ((1 << CSH) - 1));
  }
}

__global__ __launch_bounds__(256) void bucket_scan(const int* __restrict__ gcurV,
                                                   const int* __restrict__ gcurC,
                                                   int* __restrict__ ebaseV,
                                                   int* __restrict__ ebaseC) {
  __shared__ int s[256];
  int t = threadIdx.x;
  int v = (t < NBV) ? (gcurV[t] - t * CAPV) : 0;
  s[t] = v;
  __syncthreads();
  for (int d = 1; d < 256; d <<= 1) {
    int x = (t >= d) ? s[t - d] : 0;
    __syncthreads();
    s[t] += x;
    __syncthreads();
  }
  if (t < NBV) ebaseV[t] = s[t] - v;
  if (t == NBV - 1) ebaseV[NBV] = s[t];
  __syncthreads();
  int c = (t < NBC) ? (gcurC[t] - t * CAPC) : 0;
  s[t] = c;
  __syncthreads();
  for (int d = 1; d < 256; d <<= 1) {
    int x = (t >= d) ? s[t - d] : 0;
    __syncthreads();
    s[t] += x;
    __syncthreads();
  }
  if (t < NBC) ebaseC[t] = s[t] - c;
  if (t == NBC - 1) ebaseC[NBC] = s[t];
}

__global__ __launch_bounds__(256) void local_csr(
    const int* __restrict__ pairV, const int* __restrict__ pairC,
    const int* __restrict__ ebaseV, const int* __restrict__ ebaseC,
    int* __restrict__ off, int* __restrict__ adj) {
  __shared__ int cnt[1024];
  __shared__ int cur[1024];
  __shared__ int s[256];
  int tid = threadIdx.x;
  int b = blockIdx.x;
  const int* pairs;
  int m, obase, nn, sh;
  int* offp;
  if (b < NBV) {
    pairs = pairV + (size_t)b * CAPV;
    m = ebaseV[b + 1] - ebaseV[b];
    obase = ebaseV[b];
    nn = min(1024, N_VAR - (b << 10));
    sh = VSH;
    offp = off + (b << 10);
  } else {
    int bb = b - NBV;
    pairs = pairC + (size_t)bb * CAPC;
    m = ebaseC[bb + 1] - ebaseC[bb];
    obase = N_EDGE + ebaseC[bb];
    nn = min(512, N_CONS - (bb << 9));
    sh = CSH;
    offp = off + N_VAR + (bb << 9);
  }
  int mask = (1 << sh) - 1;
  for (int i = tid; i < 1024; i += 256) cnt[i] = 0;
  __syncthreads();
  for (int k = tid; k < m; k += 256) atomicAdd(&cnt[pairs[k] & mask], 1);
  __syncthreads();
  int i0 = tid * 4;
  int c0 = cnt[i0], c1 = cnt[i0 + 1], c2 = cnt[i0 + 2], c3 = cnt[i0 + 3];
  int sum = c0 + c1 + c2 + c3;
  s[tid] = sum;
  __syncthreads();
  for (int d = 1; d < 256; d <<= 1) {
    int x = (tid >= d) ? s[tid - d] : 0;
    __syncthreads();
    s[tid] += x;
    __syncthreads();
  }
  int run = obase + s[tid] - sum;
  int vals[4] = {c0, c1, c2, c3};
#pragma unroll
  for (int q = 0; q < 4; ++q) {
    int i = i0 + q;
    cur[i] = run;
    if (i < nn) offp[i] = run;
    run += vals[q];
  }
  __syncthreads();
  for (int k = tid; k < m; k += 256) {
    int pr = pairs[k];
    int p = atomicAdd(&cur[pr & mask], 1);
    adj[p] = pr >> sh;
  }
}

// ---------------- Embedding as tiled GEMM; writes bf16 table only ----------------

template <int F>
__global__ __launch_bounds__(256) void embed_mm(
    const float* __restrict__ x, const float* __restrict__ shift,
    const float* __restrict__ scale, const float* __restrict__ W1,
    const float* __restrict__ b1, const float* __restrict__ W2,
    const float* __restrict__ b2, const float* __restrict__ bi,
    const float* __restrict__ bW, uint2* __restrict__ outbf, int n) {
  __shared__ float Xs[64 * F];
  __shared__ float W1s[F][64];
  __shared__ float Hs[64][68];
  __shared__ float W2s[64][64];
  __shared__ float b1s[64], b2s[64], bWs[64], bis[64];
  int t = threadIdx.x;
  int v0 = blockIdx.x * 64;
  for (int i = t; i < F * 64; i += 256) W1s[i / 64][i % 64] = W1[i] * scale[i / 64];
  for (int i = t; i < 64 * 64; i += 256) ((float*)W2s)[i] = W2[i];
  if (t < 64) {
    float acc = b1[t];
#pragma unroll
    for (int k = 0; k < F; ++k) acc += shift[k] * scale[k] * W1[k * 64 + t];
    b1s[t] = acc;
    b2s[t] = b2[t];
    bWs[t] = bW ? bW[t] : 0.f;
    bis[t] = (bi && v0 + t < n) ? bi[v0 + t] : 0.f;
  }
  int count = (min(n, v0 + 64) - v0) * F;
  for (int i = t; i < count; i += 256) Xs[i] = x[(size_t)v0 * F + i];
  __syncthreads();

  int jt = t & 15;
  int vt = t >> 4;
  float c[4][4] = {};
#pragma unroll
  for (int k = 0; k < F; ++k) {
    float w0 = W1s[k][jt * 4], w1 = W1s[k][jt * 4 + 1];
    float w2 = W1s[k][jt * 4 + 2], w3 = W1s[k][jt * 4 + 3];
#pragma unroll
    for (int i = 0; i < 4; ++i) {
      float xv = Xs[(vt * 4 + i) * F + k];
      c[i][0] += xv * w0;
      c[i][1] += xv * w1;
      c[i][2] += xv * w2;
      c[i][3] += xv * w3;
    }
  }
#pragma unroll
  for (int i = 0; i < 4; ++i)
#pragma unroll
    for (int q = 0; q < 4; ++q)
      Hs[vt * 4 + i][jt * 4 + q] = fmaxf(c[i][q] + b1s[jt * 4 + q], 0.f);
  __syncthreads();
  float d[4][4] = {};
#pragma unroll 4
  for (int k4 = 0; k4 < 16; ++k4) {
    float4 xv[4], wv[4];
#pragma unroll
    for (int i = 0; i < 4; ++i) xv[i] = *(const float4*)&Hs[vt * 4 + i][k4 * 4];
#pragma unroll
    for (int kk = 0; kk < 4; ++kk) wv[kk] = *(const float4*)&W2s[k4 * 4 + kk][jt * 4];
#pragma unroll
    for (int i = 0; i < 4; ++i) {
      d[i][0] += xv[i].x * wv[0].x + xv[i].y * wv[1].x + xv[i].z * wv[2].x + xv[i].w * wv[3].x;
      d[i][1] += xv[i].x * wv[0].y + xv[i].y * wv[1].y + xv[i].z * wv[2].y + xv[i].w * wv[3].y;
      d[i][2] += xv[i].x * wv[0].z + xv[i].y * wv[1].z + xv[i].z * wv[2].z + xv[i].w * wv[3].z;
      d[i][3] += xv[i].x * wv[0].w + xv[i].y * wv[1].w + xv[i].z * wv[2].w + xv[i].w * wv[3].w;
    }
  }
#pragma unroll
  for (int i = 0; i < 4; ++i) {
    int v = v0 + vt * 4 + i;
    if (v < n) {
      float bv = bis[vt * 4 + i];
      float ox = fmaxf(d[i][0] + b2s[jt * 4 + 0], 0.f) + bv * bWs[jt * 4 + 0];
      float oy = fmaxf(d[i][1] + b2s[jt * 4 + 1], 0.f) + bv * bWs[jt * 4 + 1];
      float oz = fmaxf(d[i][2] + b2s[jt * 4 + 2], 0.f) + bv * bWs[jt * 4 + 2];
      float ow = fmaxf(d[i][3] + b2s[jt * 4 + 3], 0.f) + bv * bWs[jt * 4 + 3];
      outbf[(size_t)v * 16 + jt] = make_uint2(pack_bf2(ox, oy), pack_bf2(oz, ow));
    }
  }
}

// ---------------- Fused SAGE (round-6 structure; 4-deep gather, bf16 dstx) ----------------
// out = relu(mean(srcbf[neigh]) @ Wl + bl + dstbf @ Wr), 64-node tile per block

template <int OUTBF>
__global__ __launch_bounds__(256) void sage_fused(
    const uint2* __restrict__ srcbf, const uint2* __restrict__ dstbf,
    const int* __restrict__ off, const int* __restrict__ adj,
    const float* __restrict__ Wl, const float* __restrict__ bl,
    const float* __restrict__ Wr, float* __restrict__ outf,
    uint2* __restrict__ outbf, int n) {
  __shared__ float Hs[64][68];
  __shared__ float Ws[64][64];
  __shared__ float bls[64];
  int t = threadIdx.x;
  int v0 = blockIdx.x * 64;
  if (t < 64) bls[t] = bl[t];
  for (int i = t; i < 1024; i += 256) ((float4*)Ws)[i] = ((const float4*)Wl)[i];

  // Phase A: gather-mean into Hs (bf16 rows, 16 lanes/node, 4 loads in flight)
  int lane = t & 15;
  int g = t >> 4;
#pragma unroll
  for (int grp = 0; grp < 4; ++grp) {
    int r = grp * 16 + g;
    int v = v0 + r;
    float ax = 0.f, ay = 0.f, az = 0.f, aw = 0.f;
    if (v < n) {
      int s0 = off[v], s1 = off[v + 1];
      int i = s0;
      for (; i + 4 <= s1; i += 4) {
        int u0 = adj[i], u1 = adj[i + 1], u2 = adj[i + 2], u3 = adj[i + 3];
        uint2 a0 = srcbf[(size_t)u0 * 16 + lane];
        uint2 a1 = srcbf[(size_t)u1 * 16 + lane];
        uint2 a2 = srcbf[(size_t)u2 * 16 + lane];
        uint2 a3 = srcbf[(size_t)u3 * 16 + lane];
        ax += (b2f_lo(a0.x) + b2f_lo(a1.x)) + (b2f_lo(a2.x) + b2f_lo(a3.x));
        ay += (b2f_hi(a0.x) + b2f_hi(a1.x)) + (b2f_hi(a2.x) + b2f_hi(a3.x));
        az += (b2f_lo(a0.y) + b2f_lo(a1.y)) + (b2f_lo(a2.y) + b2f_lo(a3.y));
        aw += (b2f_hi(a0.y) + b2f_hi(a1.y)) + (b2f_hi(a2.y) + b2f_hi(a3.y));
      }
      if (i + 2 <= s1) {
        int u0 = adj[i], u1 = adj[i + 1];
        uint2 a0 = srcbf[(size_t)u0 * 16 + lane];
        uint2 a1 = srcbf[(size_t)u1 * 16 + lane];
        ax += b2f_lo(a0.x) + b2f_lo(a1.x);
        ay += b2f_hi(a0.x) + b2f_hi(a1.x);
        az += b2f_lo(a0.y) + b2f_lo(a1.y);
        aw += b2f_hi(a0.y) + b2f_hi(a1.y);
        i += 2;
      }
      if (i < s1) {
        uint2 a = srcbf[(size_t)adj[i] * 16 + lane];
        ax += b2f_lo(a.x);
        ay += b2f_hi(a.x);
        az += b2f_lo(a.y);
        aw += b2f_hi(a.y);
      }
      int deg = s1 - s0;
      float inv = (deg > 0) ? 1.f / (float)deg : 0.f;
      ax *= inv;
      ay *= inv;
      az *= inv;
      aw *= inv;
    }
    *(float4*)&Hs[r][lane * 4] = make_float4(ax, ay, az, aw);
  }
  __syncthreads();

  int jt = t & 15;
  int vt = t >> 4;
  float c[4][4] = {};
  auto compute = [&]() {
#pragma unroll 4
    for (int k4 = 0; k4 < 16; ++k4) {
      float4 xv[4], wv[4];
#pragma unroll
      for (int i = 0; i < 4; ++i) xv[i] = *(const float4*)&Hs[vt * 4 + i][k4 * 4];
#pragma unroll
      for (int kk = 0; kk < 4; ++kk) wv[kk] = *(const float4*)&Ws[k4 * 4 + kk][jt * 4];
#pragma unroll
      for (int i = 0; i < 4; ++i) {
        c[i][0] += xv[i].x * wv[0].x + xv[i].y * wv[1].x + xv[i].z * wv[2].x + xv[i].w * wv[3].x;
        c[i][1] += xv[i].x * wv[0].y + xv[i].y * wv[1].y + xv[i].z * wv[2].y + xv[i].w * wv[3].y;
        c[i][2] += xv[i].x * wv[0].z + xv[i].y * wv[1].z + xv[i].z * wv[2].z + xv[i].w * wv[3].z;
        c[i][3] += xv[i].x * wv[0].w + xv[i].y * wv[1].w + xv[i].z * wv[2].w + xv[i].w * wv[3].w;
      }
    }
  };
  compute();  // mean @ Wl
  __syncthreads();
  // stage dstx tile (bf16 -> fp32) + Wr
#pragma unroll
  for (int r = 0; r < 4; ++r) {
    int idx = t + 256 * r;
    int rowi = idx >> 4, f4 = idx & 15;
    int v = v0 + rowi;
    uint2 val = (v < n) ? dstbf[(size_t)v * 16 + f4] : make_uint2(0u, 0u);
    *(float4*)&Hs[rowi][f4 * 4] =
        make_float4(b2f_lo(val.x), b2f_hi(val.x), b2f_lo(val.y), b2f_hi(val.y));
    ((float4*)Ws)[idx] = ((const float4*)Wr)[idx];
  }
  __syncthreads();
  compute();  // += dstx @ Wr

#pragma unroll
  for (int i = 0; i < 4; ++i) {
    int v = v0 + vt * 4 + i;
    if (v < n) {
      float ox = fmaxf(c[i][0] + bls[jt * 4 + 0], 0.f);
      float oy = fmaxf(c[i][1] + bls[jt * 4 + 1], 0.f);
      float oz = fmaxf(c[i][2] + bls[jt * 4 + 2], 0.f);
      float ow = fmaxf(c[i][3] + bls[jt * 4 + 3], 0.f);
      if (OUTBF) {
        outbf[(size_t)v * 16 + jt] = make_uint2(pack_bf2(ox, oy), pack_bf2(oz, ow));
      } else {
        *(float4*)&outf[(size_t)v * 64 + jt * 4] = make_float4(ox, oy, oz, ow);
      }
    }
  }
}

// ---------------- host ----------------

extern "C" void kernel_launch(void* const* d_in, const int* in_sizes, int n_in,
                              void* d_out, int out_size, void* d_ws, size_t ws_size,
                              hipStream_t stream) {
  const float* cons_x = (const float*)d_in[0];
  const float* var_x  = (const float*)d_in[1];
  const int*   eidx   = (const int*)d_in[2];
  const float* bi     = (const float*)d_in[4];
  const float* c_sh   = (const float*)d_in[5];
  const float* c_sc   = (const float*)d_in[6];
  const float* v_sh   = (const float*)d_in[7];
  const float* v_sc   = (const float*)d_in[8];
  const float* cW1 = (const float*)d_in[11];
  const float* cb1 = (const float*)d_in[12];
  const float* cW2 = (const float*)d_in[13];
  const float* cb2 = (const float*)d_in[14];
  const float* vW1 = (const float*)d_in[15];
  const float* vb1 = (const float*)d_in[16];
  const float* vW2 = (const float*)d_in[17];
  const float* vb2 = (const float*)d_in[18];
  const float* bW  = (const float*)d_in[19];
  const float* Wl_cv = (const float*)d_in[20];
  const float* bl_cv = (const float*)d_in[21];
  const float* Wr_cv = (const float*)d_in[22];
  const float* Wl_vc = (const float*)d_in[23];
  const float* bl_vc = (const float*)d_in[24];
  const float* Wr_vc = (const float*)d_in[25];

  const int* row = eidx;           // [E] constraint index per edge
  const int* col = eidx + N_EDGE;  // [E] variable index per edge

  char* ws = (char*)d_ws;
  size_t o = 0;
  auto alloc = [&](size_t bytes) {
    char* p = ws + o;
    o = (o + bytes + 255) & ~(size_t)255;
    return p;
  };
  int* off    = (int*)alloc((N_TOT + 1) * sizeof(int));
  int* adj    = (int*)alloc((size_t)2 * N_EDGE * sizeof(int));
  int* pairV  = (int*)alloc((size_t)NBV * CAPV * sizeof(int));
  int* pairC  = (int*)alloc((size_t)NBC * CAPC * sizeof(int));
  int* gcurV  = (int*)alloc(256 * sizeof(int));
  int* gcurC  = (int*)alloc(256 * sizeof(int));
  int* ebaseV = (int*)alloc(256 * sizeof(int));
  int* ebaseC = (int*)alloc(256 * sizeof(int));
  uint2* consEbf = (uint2*)alloc((size_t)N_CONS * EMB * 2);
  uint2* varEbf  = (uint2*)alloc((size_t)N_VAR * EMB * 2);
  uint2* cons1bf = (uint2*)alloc((size_t)N_CONS * EMB * 2);
  uint2* var1bf  = (uint2*)alloc((size_t)N_VAR * EMB * 2);
  float* var_out = (float*)d_out;

  csr_init<<<1, 256, 0, stream>>>(gcurV, gcurC, off);
  bucket_scatter<<<512, 256, 0, stream>>>(row, col, gcurV, gcurC, pairV, pairC);
  bucket_scan<<<1, 256, 0, stream>>>(gcurV, gcurC, ebaseV, ebaseC);
  local_csr<<<NBV + NBC, 256, 0, stream>>>(pairV, pairC, ebaseV, ebaseC, off, adj);

  embed_mm<5><<<(N_CONS + 63) / 64, 256, 0, stream>>>(
      cons_x, c_sh, c_sc, cW1, cb1, cW2, cb2, nullptr, nullptr, consEbf, N_CONS);
  embed_mm<19><<<(N_VAR + 63) / 64, 256, 0, stream>>>(
      var_x, v_sh, v_sc, vW1, vb1, vW2, vb2, bi, bW, varEbf, N_VAR);

  // layer 0, var side: var1bf = relu(mean_cons @ Wl_cv + bl + varE @ Wr_cv)  (bf16 only;
  // consumed solely as layer-1 dstx — d_out is fully overwritten by layer 1)
  sage_fused<1><<<(N_VAR + 63) / 64, 256, 0, stream>>>(
      consEbf, varEbf, off, adj, Wl_cv, bl_cv, Wr_cv, nullptr, var1bf, N_VAR);
  // layer 0, cons side -> bf16 (gather source of layer 1)
  sage_fused<1><<<(N_CONS + 63) / 64, 256, 0, stream>>>(
      varEbf, consEbf, off + N_VAR, adj, Wl_vc, bl_vc, Wr_vc, nullptr, cons1bf,
      N_CONS);
  // layer 1, var side only -> fp32 d_out
  sage_fused<0><<<(N_VAR + 63) / 64, 256, 0, stream>>>(
      cons1bf, var1bf, off, adj, Wl_cv + 4096, bl_cv + 64, Wr_cv + 4096,
      var_out, nullptr, N_VAR);
}

// Round 8
// 325.845 us; speedup vs baseline: 11.1818x; 1.3857x over previous
//
#include <hip/hip_runtime.h>

#define N_CONS 100000
#define N_VAR  200000
#define N_TOT  (N_CONS + N_VAR)
#define N_EDGE 2000000
#define EMB 64

#define VSH 10
#define NBV 196   // ceil(200000/1024)
#define CAPV 12288
#define CSH 9
#define NBC 196   // ceil(100000/512)
#define CAPC 12288

typedef unsigned short u16;
typedef __attribute__((ext_vector_type(8))) short bf16x8;
typedef __attribute__((ext_vector_type(4))) float f32x4;

// ---------------- bf16 helpers ----------------

__device__ __forceinline__ float b2f_lo(unsigned u) {
  union { unsigned i; float f; } c;
  c.i = u << 16;
  return c.f;
}
__device__ __forceinline__ float b2f_hi(unsigned u) {
  union { unsigned i; float f; } c;
  c.i = u & 0xFFFF0000u;
  return c.f;
}
__device__ __forceinline__ unsigned pack_bf2(float a, float b) {
  unsigned ua = __float_as_uint(a), ub = __float_as_uint(b);
  unsigned ra = (ua + 0x7FFFu + ((ua >> 16) & 1u)) >> 16;
  unsigned rb = (ub + 0x7FFFu + ((ub >> 16) & 1u)) >> 16;
  return ra | (rb << 16);
}
__device__ __forceinline__ u16 f2bf(float a) {
  unsigned ua = __float_as_uint(a);
  return (u16)((ua + 0x7FFFu + ((ua >> 16) & 1u)) >> 16);
}

// ---------------- CSR build: bucketed counting sort ----------------

__global__ __launch_bounds__(256) void csr_init(int* __restrict__ gcurV,
                                                int* __restrict__ gcurC,
                                                int* __restrict__ off) {
  int t = threadIdx.x;
  if (t < NBV) gcurV[t] = t * CAPV;
  if (t < NBC) gcurC[t] = t * CAPC;
  if (t == 0) off[N_TOT] = 2 * N_EDGE;
}

__global__ __launch_bounds__(256) void bucket_scatter(
    const int* __restrict__ row, const int* __restrict__ col,
    int* __restrict__ gcurV, int* __restrict__ gcurC,
    int* __restrict__ pairV, int* __restrict__ pairC) {
  __shared__ int hV[NBV];
  __shared__ int hC[NBC];
  int tid = threadIdx.x;
  int chunk = (N_EDGE + gridDim.x - 1) / gridDim.x;
  int lo = blockIdx.x * chunk;
  int hi = min(N_EDGE, lo + chunk);
  for (int i = tid; i < NBV; i += 256) hV[i] = 0;
  for (int i = tid; i < NBC; i += 256) hC[i] = 0;
  __syncthreads();
  for (int e = lo + tid; e < hi; e += 256) {
    atomicAdd(&hV[col[e] >> VSH], 1);
    atomicAdd(&hC[row[e] >> CSH], 1);
  }
  __syncthreads();
  for (int i = tid; i < NBV; i += 256) {
    int c = hV[i];
    hV[i] = c ? atomicAdd(&gcurV[i], c) : 0;
  }
  for (int i = tid; i < NBC; i += 256) {
    int c = hC[i];
    hC[i] = c ? atomicAdd(&gcurC[i], c) : 0;
  }
  __syncthreads();
  for (int e = lo + tid; e < hi; e += 256) {
    int r = row[e], c = col[e];
    int p = atomicAdd(&hV[c >> VSH], 1);
    pairV[p] = (r << VSH) | (c & ((1 << VSH) - 1));
    int q = atomicAdd(&hC[r >> CSH], 1);
    pairC[q] = (c << CSH) | (r & ((1 << CSH) - 1));
  }
}

__global__ __launch_bounds__(256) void bucket_scan(const int* __restrict__ gcurV,
                                                   const int* __restrict__ gcurC,
                                                   int* __restrict__ ebaseV,
                                                   int* __restrict__ ebaseC) {
  __shared__ int s[256];
  int t = threadIdx.x;
  int v = (t < NBV) ? (gcurV[t] - t * CAPV) : 0;
  s[t] = v;
  __syncthreads();
  for (int d = 1; d < 256; d <<= 1) {
    int x = (t >= d) ? s[t - d] : 0;
    __syncthreads();
    s[t] += x;
    __syncthreads();
  }
  if (t < NBV) ebaseV[t] = s[t] - v;
  if (t == NBV - 1) ebaseV[NBV] = s[t];
  __syncthreads();
  int c = (t < NBC) ? (gcurC[t] - t * CAPC) : 0;
  s[t] = c;
  __syncthreads();
  for (int d = 1; d < 256; d <<= 1) {
    int x = (t >= d) ? s[t - d] : 0;
    __syncthreads();
    s[t] += x;
    __syncthreads();
  }
  if (t < NBC) ebaseC[t] = s[t] - c;
  if (t == NBC - 1) ebaseC[NBC] = s[t];
}

__global__ __launch_bounds__(256) void local_csr(
    const int* __restrict__ pairV, const int* __restrict__ pairC,
    const int* __restrict__ ebaseV, const int* __restrict__ ebaseC,
    int* __restrict__ off, int* __restrict__ adj) {
  __shared__ int cnt[1024];
  __shared__ int cur[1024];
  __shared__ int s[256];
  int tid = threadIdx.x;
  int b = blockIdx.x;
  const int* pairs;
  int m, obase, nn, sh;
  int* offp;
  if (b < NBV) {
    pairs = pairV + (size_t)b * CAPV;
    m = ebaseV[b + 1] - ebaseV[b];
    obase = ebaseV[b];
    nn = min(1024, N_VAR - (b << 10));
    sh = VSH;
    offp = off + (b << 10);
  } else {
    int bb = b - NBV;
    pairs = pairC + (size_t)bb * CAPC;
    m = ebaseC[bb + 1] - ebaseC[bb];
    obase = N_EDGE + ebaseC[bb];
    nn = min(512, N_CONS - (bb << 9));
    sh = CSH;
    offp = off + N_VAR + (bb << 9);
  }
  int mask = (1 << sh) - 1;
  for (int i = tid; i < 1024; i += 256) cnt[i] = 0;
  __syncthreads();
  for (int k = tid; k < m; k += 256) atomicAdd(&cnt[pairs[k] & mask], 1);
  __syncthreads();
  int i0 = tid * 4;
  int c0 = cnt[i0], c1 = cnt[i0 + 1], c2 = cnt[i0 + 2], c3 = cnt[i0 + 3];
  int sum = c0 + c1 + c2 + c3;
  s[tid] = sum;
  __syncthreads();
  for (int d = 1; d < 256; d <<= 1) {
    int x = (tid >= d) ? s[tid - d] : 0;
    __syncthreads();
    s[tid] += x;
    __syncthreads();
  }
  int run = obase + s[tid] - sum;
  int vals[4] = {c0, c1, c2, c3};
#pragma unroll
  for (int q = 0; q < 4; ++q) {
    int i = i0 + q;
    cur[i] = run;
    if (i < nn) offp[i] = run;
    run += vals[q];
  }
  __syncthreads();
  for (int k = tid; k < m; k += 256) {
    int pr = pairs[k];
    int p = atomicAdd(&cur[pr & mask], 1);
    adj[p] = pr >> sh;
  }
}

// ---------------- Embedding as tiled GEMM; writes bf16 table only ----------------

template <int F>
__global__ __launch_bounds__(256) void embed_mm(
    const float* __restrict__ x, const float* __restrict__ shift,
    const float* __restrict__ scale, const float* __restrict__ W1,
    const float* __restrict__ b1, const float* __restrict__ W2,
    const float* __restrict__ b2, const float* __restrict__ bi,
    const float* __restrict__ bW, uint2* __restrict__ outbf, int n) {
  __shared__ float Xs[64 * F];
  __shared__ float W1s[F][64];
  __shared__ float Hs[64][68];
  __shared__ float W2s[64][64];
  __shared__ float b1s[64], b2s[64], bWs[64], bis[64];
  int t = threadIdx.x;
  int v0 = blockIdx.x * 64;
  for (int i = t; i < F * 64; i += 256) W1s[i / 64][i % 64] = W1[i] * scale[i / 64];
  for (int i = t; i < 64 * 64; i += 256) ((float*)W2s)[i] = W2[i];
  if (t < 64) {
    float acc = b1[t];
#pragma unroll
    for (int k = 0; k < F; ++k) acc += shift[k] * scale[k] * W1[k * 64 + t];
    b1s[t] = acc;
    b2s[t] = b2[t];
    bWs[t] = bW ? bW[t] : 0.f;
    bis[t] = (bi && v0 + t < n) ? bi[v0 + t] : 0.f;
  }
  int count = (min(n, v0 + 64) - v0) * F;
  for (int i = t; i < count; i += 256) Xs[i] = x[(size_t)v0 * F + i];
  __syncthreads();

  int jt = t & 15;
  int vt = t >> 4;
  float c[4][4] = {};
#pragma unroll
  for (int k = 0; k < F; ++k) {
    float w0 = W1s[k][jt * 4], w1 = W1s[k][jt * 4 + 1];
    float w2 = W1s[k][jt * 4 + 2], w3 = W1s[k][jt * 4 + 3];
#pragma unroll
    for (int i = 0; i < 4; ++i) {
      float xv = Xs[(vt * 4 + i) * F + k];
      c[i][0] += xv * w0;
      c[i][1] += xv * w1;
      c[i][2] += xv * w2;
      c[i][3] += xv * w3;
    }
  }
#pragma unroll
  for (int i = 0; i < 4; ++i)
#pragma unroll
    for (int q = 0; q < 4; ++q)
      Hs[vt * 4 + i][jt * 4 + q] = fmaxf(c[i][q] + b1s[jt * 4 + q], 0.f);
  __syncthreads();
  float d[4][4] = {};
#pragma unroll 4
  for (int k4 = 0; k4 < 16; ++k4) {
    float4 xv[4], wv[4];
#pragma unroll
    for (int i = 0; i < 4; ++i) xv[i] = *(const float4*)&Hs[vt * 4 + i][k4 * 4];
#pragma unroll
    for (int kk = 0; kk < 4; ++kk) wv[kk] = *(const float4*)&W2s[k4 * 4 + kk][jt * 4];
#pragma unroll
    for (int i = 0; i < 4; ++i) {
      d[i][0] += xv[i].x * wv[0].x + xv[i].y * wv[1].x + xv[i].z * wv[2].x + xv[i].w * wv[3].x;
      d[i][1] += xv[i].x * wv[0].y + xv[i].y * wv[1].y + xv[i].z * wv[2].y + xv[i].w * wv[3].y;
      d[i][2] += xv[i].x * wv[0].z + xv[i].y * wv[1].z + xv[i].z * wv[2].z + xv[i].w * wv[3].z;
      d[i][3] += xv[i].x * wv[0].w + xv[i].y * wv[1].w + xv[i].z * wv[2].w + xv[i].w * wv[3].w;
    }
  }
#pragma unroll
  for (int i = 0; i < 4; ++i) {
    int v = v0 + vt * 4 + i;
    if (v < n) {
      float bv = bis[vt * 4 + i];
      float ox = fmaxf(d[i][0] + b2s[jt * 4 + 0], 0.f) + bv * bWs[jt * 4 + 0];
      float oy = fmaxf(d[i][1] + b2s[jt * 4 + 1], 0.f) + bv * bWs[jt * 4 + 1];
      float oz = fmaxf(d[i][2] + b2s[jt * 4 + 2], 0.f) + bv * bWs[jt * 4 + 2];
      float ow = fmaxf(d[i][3] + b2s[jt * 4 + 3], 0.f) + bv * bWs[jt * 4 + 3];
      outbf[(size_t)v * 16 + jt] = make_uint2(pack_bf2(ox, oy), pack_bf2(oz, ow));
    }
  }
}

// ---------------- Fused SAGE with MFMA dense phase ----------------
// out = relu(mean(srcbf[neigh]) @ Wl + bl + dstbf @ Wr), 64-node tile per block
// LDS: Hs (X tile, bf16 [64][72]), Ws (W^T, bf16 [64][72]) -> ~18.7 KB, 8 blocks/CU

template <int OUTBF>
__global__ __launch_bounds__(256) void sage_mfma(
    const uint2* __restrict__ srcbf, const uint2* __restrict__ dstbf,
    const int* __restrict__ off, const int* __restrict__ adj,
    const float* __restrict__ Wl, const float* __restrict__ bl,
    const float* __restrict__ Wr, float* __restrict__ outf,
    u16* __restrict__ outbf, int n) {
  __shared__ u16 Hs[64][72];
  __shared__ u16 Ws[64][72];  // W^T: Ws[n][k]
  __shared__ float bls[64];
  int t = threadIdx.x;
  int v0 = blockIdx.x * 64;
  if (t < 64) bls[t] = bl[t];

  // stage Wl^T as bf16 (coalesced 256B global reads, packed b128 LDS writes)
  int sn = t & 63;   // output col n (= lane within wave)
  int kq = t >> 6;   // k-quarter (= wave id)
  {
    unsigned pk[8];
#pragma unroll
    for (int i = 0; i < 8; ++i) {
      float w0 = Wl[(size_t)(kq * 16 + 2 * i) * 64 + sn];
      float w1 = Wl[(size_t)(kq * 16 + 2 * i + 1) * 64 + sn];
      pk[i] = pack_bf2(w0, w1);
    }
    *(uint4*)&Ws[sn][kq * 16] = make_uint4(pk[0], pk[1], pk[2], pk[3]);
    *(uint4*)&Ws[sn][kq * 16 + 8] = make_uint4(pk[4], pk[5], pk[6], pk[7]);
  }

  // Phase A: gather-mean into Hs (bf16 rows, 16 lanes/node, 4 loads in flight)
  int lane = t & 15;
  int g = t >> 4;
#pragma unroll
  for (int grp = 0; grp < 4; ++grp) {
    int r = grp * 16 + g;
    int v = v0 + r;
    float ax = 0.f, ay = 0.f, az = 0.f, aw = 0.f;
    if (v < n) {
      int s0 = off[v], s1 = off[v + 1];
      int i = s0;
      for (; i + 4 <= s1; i += 4) {
        int u0 = adj[i], u1 = adj[i + 1], u2 = adj[i + 2], u3 = adj[i + 3];
        uint2 a0 = srcbf[(size_t)u0 * 16 + lane];
        uint2 a1 = srcbf[(size_t)u1 * 16 + lane];
        uint2 a2 = srcbf[(size_t)u2 * 16 + lane];
        uint2 a3 = srcbf[(size_t)u3 * 16 + lane];
        ax += (b2f_lo(a0.x) + b2f_lo(a1.x)) + (b2f_lo(a2.x) + b2f_lo(a3.x));
        ay += (b2f_hi(a0.x) + b2f_hi(a1.x)) + (b2f_hi(a2.x) + b2f_hi(a3.x));
        az += (b2f_lo(a0.y) + b2f_lo(a1.y)) + (b2f_lo(a2.y) + b2f_lo(a3.y));
        aw += (b2f_hi(a0.y) + b2f_hi(a1.y)) + (b2f_hi(a2.y) + b2f_hi(a3.y));
      }
      if (i + 2 <= s1) {
        int u0 = adj[i], u1 = adj[i + 1];
        uint2 a0 = srcbf[(size_t)u0 * 16 + lane];
        uint2 a1 = srcbf[(size_t)u1 * 16 + lane];
        ax += b2f_lo(a0.x) + b2f_lo(a1.x);
        ay += b2f_hi(a0.x) + b2f_hi(a1.x);
        az += b2f_lo(a0.y) + b2f_lo(a1.y);
        aw += b2f_hi(a0.y) + b2f_hi(a1.y);
        i += 2;
      }
      if (i < s1) {
        uint2 a = srcbf[(size_t)adj[i] * 16 + lane];
        ax += b2f_lo(a.x);
        ay += b2f_hi(a.x);
        az += b2f_lo(a.y);
        aw += b2f_hi(a.y);
      }
      int deg = s1 - s0;
      float inv = (deg > 0) ? 1.f / (float)deg : 0.f;
      ax *= inv;
      ay *= inv;
      az *= inv;
      aw *= inv;
    }
    *(uint2*)&Hs[r][lane * 4] = make_uint2(pack_bf2(ax, ay), pack_bf2(az, aw));
  }
  __syncthreads();

  // MFMA phase 1: acc = mean @ Wl
  int l = t & 63;
  int w = t >> 6;
  int m0 = w * 16;
  int rA = m0 + (l & 15);
  int koffA = (l >> 4) * 8;
  f32x4 acc[4] = {};
  {
    bf16x8 a0 = *(const bf16x8*)&Hs[rA][koffA];
    bf16x8 a1 = *(const bf16x8*)&Hs[rA][32 + koffA];
#pragma unroll
    for (int cb = 0; cb < 4; ++cb) {
      int nB = cb * 16 + (l & 15);
      bf16x8 b0 = *(const bf16x8*)&Ws[nB][koffA];
      bf16x8 b1 = *(const bf16x8*)&Ws[nB][32 + koffA];
      acc[cb] = __builtin_amdgcn_mfma_f32_16x16x32_bf16(a0, b0, acc[cb], 0, 0, 0);
      acc[cb] = __builtin_amdgcn_mfma_f32_16x16x32_bf16(a1, b1, acc[cb], 0, 0, 0);
    }
  }
  __syncthreads();

  // restage: Hs <- dst tile (bf16 copy), Ws <- Wr^T
#pragma unroll
  for (int r4 = 0; r4 < 4; ++r4) {
    int idx = t + 256 * r4;
    int rowi = idx >> 4, f4 = idx & 15;
    int v = v0 + rowi;
    uint2 val = (v < n) ? dstbf[(size_t)v * 16 + f4] : make_uint2(0u, 0u);
    *(uint2*)&Hs[rowi][f4 * 4] = val;
  }
  {
    unsigned pk[8];
#pragma unroll
    for (int i = 0; i < 8; ++i) {
      float w0 = Wr[(size_t)(kq * 16 + 2 * i) * 64 + sn];
      float w1 = Wr[(size_t)(kq * 16 + 2 * i + 1) * 64 + sn];
      pk[i] = pack_bf2(w0, w1);
    }
    *(uint4*)&Ws[sn][kq * 16] = make_uint4(pk[0], pk[1], pk[2], pk[3]);
    *(uint4*)&Ws[sn][kq * 16 + 8] = make_uint4(pk[4], pk[5], pk[6], pk[7]);
  }
  __syncthreads();

  // MFMA phase 2: acc += dst @ Wr
  {
    bf16x8 a0 = *(const bf16x8*)&Hs[rA][koffA];
    bf16x8 a1 = *(const bf16x8*)&Hs[rA][32 + koffA];
#pragma unroll
    for (int cb = 0; cb < 4; ++cb) {
      int nB = cb * 16 + (l & 15);
      bf16x8 b0 = *(const bf16x8*)&Ws[nB][koffA];
      bf16x8 b1 = *(const bf16x8*)&Ws[nB][32 + koffA];
      acc[cb] = __builtin_amdgcn_mfma_f32_16x16x32_bf16(a0, b0, acc[cb], 0, 0, 0);
      acc[cb] = __builtin_amdgcn_mfma_f32_16x16x32_bf16(a1, b1, acc[cb], 0, 0, 0);
    }
  }

  // epilogue: bias + relu + store (D: col=l&15 within cb*16, row=(l>>4)*4+j)
#pragma unroll
  for (int cb = 0; cb < 4; ++cb) {
    int colc = cb * 16 + (l & 15);
    float bias = bls[colc];
#pragma unroll
    for (int j = 0; j < 4; ++j) {
      int rowc = m0 + (l >> 4) * 4 + j;
      int v = v0 + rowc;
      if (v < n) {
        float val = fmaxf(acc[cb][j] + bias, 0.f);
        if (OUTBF) {
          outbf[(size_t)v * 64 + colc] = f2bf(val);
        } else {
          outf[(size_t)v * 64 + colc] = val;
        }
      }
    }
  }
}

// ---------------- host ----------------

extern "C" void kernel_launch(void* const* d_in, const int* in_sizes, int n_in,
                              void* d_out, int out_size, void* d_ws, size_t ws_size,
                              hipStream_t stream) {
  const float* cons_x = (const float*)d_in[0];
  const float* var_x  = (const float*)d_in[1];
  const int*   eidx   = (const int*)d_in[2];
  const float* bi     = (const float*)d_in[4];
  const float* c_sh   = (const float*)d_in[5];
  const float* c_sc   = (const float*)d_in[6];
  const float* v_sh   = (const float*)d_in[7];
  const float* v_sc   = (const float*)d_in[8];
  const float* cW1 = (const float*)d_in[11];
  const float* cb1 = (const float*)d_in[12];
  const float* cW2 = (const float*)d_in[13];
  const float* cb2 = (const float*)d_in[14];
  const float* vW1 = (const float*)d_in[15];
  const float* vb1 = (const float*)d_in[16];
  const float* vW2 = (const float*)d_in[17];
  const float* vb2 = (const float*)d_in[18];
  const float* bW  = (const float*)d_in[19];
  const float* Wl_cv = (const float*)d_in[20];
  const float* bl_cv = (const float*)d_in[21];
  const float* Wr_cv = (const float*)d_in[22];
  const float* Wl_vc = (const float*)d_in[23];
  const float* bl_vc = (const float*)d_in[24];
  const float* Wr_vc = (const float*)d_in[25];

  const int* row = eidx;           // [E] constraint index per edge
  const int* col = eidx + N_EDGE;  // [E] variable index per edge

  char* ws = (char*)d_ws;
  size_t o = 0;
  auto alloc = [&](size_t bytes) {
    char* p = ws + o;
    o = (o + bytes + 255) & ~(size_t)255;
    return p;
  };
  int* off    = (int*)alloc((N_TOT + 1) * sizeof(int));
  int* adj    = (int*)alloc((size_t)2 * N_EDGE * sizeof(int));
  int* pairV  = (int*)alloc((size_t)NBV * CAPV * sizeof(int));
  int* pairC  = (int*)alloc((size_t)NBC * CAPC * sizeof(int));
  int* gcurV  = (int*)alloc(256 * sizeof(int));
  int* gcurC  = (int*)alloc(256 * sizeof(int));
  int* ebaseV = (int*)alloc(256 * sizeof(int));
  int* ebaseC = (int*)alloc(256 * sizeof(int));
  uint2* consEbf = (uint2*)alloc((size_t)N_CONS * EMB * 2);
  uint2* varEbf  = (uint2*)alloc((size_t)N_VAR * EMB * 2);
  uint2* cons1bf = (uint2*)alloc((size_t)N_CONS * EMB * 2);
  uint2* var1bf  = (uint2*)alloc((size_t)N_VAR * EMB * 2);
  float* var_out = (float*)d_out;

  csr_init<<<1, 256, 0, stream>>>(gcurV, gcurC, off);
  bucket_scatter<<<512, 256, 0, stream>>>(row, col, gcurV, gcurC, pairV, pairC);
  bucket_scan<<<1, 256, 0, stream>>>(gcurV, gcurC, ebaseV, ebaseC);
  local_csr<<<NBV + NBC, 256, 0, stream>>>(pairV, pairC, ebaseV, ebaseC, off, adj);

  embed_mm<5><<<(N_CONS + 63) / 64, 256, 0, stream>>>(
      cons_x, c_sh, c_sc, cW1, cb1, cW2, cb2, nullptr, nullptr, consEbf, N_CONS);
  embed_mm<19><<<(N_VAR + 63) / 64, 256, 0, stream>>>(
      var_x, v_sh, v_sc, vW1, vb1, vW2, vb2, bi, bW, varEbf, N_VAR);

  // layer 0, var side: var1bf = relu(mean_cons @ Wl_cv + bl + varE @ Wr_cv)
  sage_mfma<1><<<(N_VAR + 63) / 64, 256, 0, stream>>>(
      consEbf, varEbf, off, adj, Wl_cv, bl_cv, Wr_cv, nullptr, (u16*)var1bf,
      N_VAR);
  // layer 0, cons side -> bf16 (gather source of layer 1)
  sage_mfma<1><<<(N_CONS + 63) / 64, 256, 0, stream>>>(
      varEbf, consEbf, off + N_VAR, adj, Wl_vc, bl_vc, Wr_vc, nullptr,
      (u16*)cons1bf, N_CONS);
  // layer 1, var side only -> fp32 d_out
  sage_mfma<0><<<(N_VAR + 63) / 64, 256, 0, stream>>>(
      cons1bf, var1bf, off, adj, Wl_cv + 4096, bl_cv + 64, Wr_cv + 4096,
      var_out, nullptr, N_VAR);
}

// Round 9
// 281.001 us; speedup vs baseline: 12.9663x; 1.1596x over previous
//
#include <hip/hip_runtime.h>

#define N_CONS 100000
#define N_VAR  200000
#define N_TOT  (N_CONS + N_VAR)
#define N_EDGE 2000000
#define EMB 64

#define VSH 10
#define NBV 196   // ceil(200000/1024)
#define CAPV 12288
#define CSH 9
#define NBC 196   // ceil(100000/512)
#define CAPC 12288

typedef unsigned short u16;
typedef __attribute__((ext_vector_type(8))) short bf16x8;
typedef __attribute__((ext_vector_type(4))) float f32x4;

// ---------------- bf16 helpers ----------------

__device__ __forceinline__ float b2f_lo(unsigned u) {
  union { unsigned i; float f; } c;
  c.i = u << 16;
  return c.f;
}
__device__ __forceinline__ float b2f_hi(unsigned u) {
  union { unsigned i; float f; } c;
  c.i = u & 0xFFFF0000u;
  return c.f;
}
__device__ __forceinline__ unsigned pack_bf2(float a, float b) {
  unsigned ua = __float_as_uint(a), ub = __float_as_uint(b);
  unsigned ra = (ua + 0x7FFFu + ((ua >> 16) & 1u)) >> 16;
  unsigned rb = (ub + 0x7FFFu + ((ub >> 16) & 1u)) >> 16;
  return ra | (rb << 16);
}
__device__ __forceinline__ u16 f2bf(float a) {
  unsigned ua = __float_as_uint(a);
  return (u16)((ua + 0x7FFFu + ((ua >> 16) & 1u)) >> 16);
}

// ---------------- CSR build: bucketed counting sort ----------------

__global__ __launch_bounds__(256) void csr_init(int* __restrict__ gcurV,
                                                int* __restrict__ gcurC,
                                                int* __restrict__ off) {
  int t = threadIdx.x;
  if (t < NBV) gcurV[t] = t * CAPV;
  if (t < NBC) gcurC[t] = t * CAPC;
  if (t == 0) off[N_TOT] = 2 * N_EDGE;
}

__global__ __launch_bounds__(256) void bucket_scatter(
    const int* __restrict__ row, const int* __restrict__ col,
    int* __restrict__ gcurV, int* __restrict__ gcurC,
    int* __restrict__ pairV, int* __restrict__ pairC) {
  __shared__ int hV[NBV];
  __shared__ int hC[NBC];
  int tid = threadIdx.x;
  int chunk = (N_EDGE + gridDim.x - 1) / gridDim.x;
  int lo = blockIdx.x * chunk;
  int hi = min(N_EDGE, lo + chunk);
  for (int i = tid; i < NBV; i += 256) hV[i] = 0;
  for (int i = tid; i < NBC; i += 256) hC[i] = 0;
  __syncthreads();
  for (int e = lo + tid; e < hi; e += 256) {
    atomicAdd(&hV[col[e] >> VSH], 1);
    atomicAdd(&hC[row[e] >> CSH], 1);
  }
  __syncthreads();
  for (int i = tid; i < NBV; i += 256) {
    int c = hV[i];
    hV[i] = c ? atomicAdd(&gcurV[i], c) : 0;
  }
  for (int i = tid; i < NBC; i += 256) {
    int c = hC[i];
    hC[i] = c ? atomicAdd(&gcurC[i], c) : 0;
  }
  __syncthreads();
  for (int e = lo + tid; e < hi; e += 256) {
    int r = row[e], c = col[e];
    int p = atomicAdd(&hV[c >> VSH], 1);
    pairV[p] = (r << VSH) | (c & ((1 << VSH) - 1));
    int q = atomicAdd(&hC[r >> CSH], 1);
    pairC[q] = (c << CSH) | (r & ((1 << CSH) - 1));
  }
}

__global__ __launch_bounds__(256) void bucket_scan(const int* __restrict__ gcurV,
                                                   const int* __restrict__ gcurC,
                                                   int* __restrict__ ebaseV,
                                                   int* __restrict__ ebaseC) {
  __shared__ int s[256];
  int t = threadIdx.x;
  int v = (t < NBV) ? (gcurV[t] - t * CAPV) : 0;
  s[t] = v;
  __syncthreads();
  for (int d = 1; d < 256; d <<= 1) {
    int x = (t >= d) ? s[t - d] : 0;
    __syncthreads();
    s[t] += x;
    __syncthreads();
  }
  if (t < NBV) ebaseV[t] = s[t] - v;
  if (t == NBV - 1) ebaseV[NBV] = s[t];
  __syncthreads();
  int c = (t < NBC) ? (gcurC[t] - t * CAPC) : 0;
  s[t] = c;
  __syncthreads();
  for (int d = 1; d < 256; d <<= 1) {
    int x = (t >= d) ? s[t - d] : 0;
    __syncthreads();
    s[t] += x;
    __syncthreads();
  }
  if (t < NBC) ebaseC[t] = s[t] - c;
  if (t == NBC - 1) ebaseC[NBC] = s[t];
}

__global__ __launch_bounds__(256) void local_csr(
    const int* __restrict__ pairV, const int* __restrict__ pairC,
    const int* __restrict__ ebaseV, const int* __restrict__ ebaseC,
    int* __restrict__ off, int* __restrict__ adj) {
  __shared__ int cnt[1024];
  __shared__ int cur[1024];
  __shared__ int s[256];
  int tid = threadIdx.x;
  int b = blockIdx.x;
  const int* pairs;
  int m, obase, nn, sh;
  int* offp;
  if (b < NBV) {
    pairs = pairV + (size_t)b * CAPV;
    m = ebaseV[b + 1] - ebaseV[b];
    obase = ebaseV[b];
    nn = min(1024, N_VAR - (b << 10));
    sh = VSH;
    offp = off + (b << 10);
  } else {
    int bb = b - NBV;
    pairs = pairC + (size_t)bb * CAPC;
    m = ebaseC[bb + 1] - ebaseC[bb];
    obase = N_EDGE + ebaseC[bb];
    nn = min(512, N_CONS - (bb << 9));
    sh = CSH;
    offp = off + N_VAR + (bb << 9);
  }
  int mask = (1 << sh) - 1;
  for (int i = tid; i < 1024; i += 256) cnt[i] = 0;
  __syncthreads();
  for (int k = tid; k < m; k += 256) atomicAdd(&cnt[pairs[k] & mask], 1);
  __syncthreads();
  int i0 = tid * 4;
  int c0 = cnt[i0], c1 = cnt[i0 + 1], c2 = cnt[i0 + 2], c3 = cnt[i0 + 3];
  int sum = c0 + c1 + c2 + c3;
  s[tid] = sum;
  __syncthreads();
  for (int d = 1; d < 256; d <<= 1) {
    int x = (tid >= d) ? s[tid - d] : 0;
    __syncthreads();
    s[tid] += x;
    __syncthreads();
  }
  int run = obase + s[tid] - sum;
  int vals[4] = {c0, c1, c2, c3};
#pragma unroll
  for (int q = 0; q < 4; ++q) {
    int i = i0 + q;
    cur[i] = run;
    if (i < nn) offp[i] = run;
    run += vals[q];
  }
  __syncthreads();
  for (int k = tid; k < m; k += 256) {
    int pr = pairs[k];
    int p = atomicAdd(&cur[pr & mask], 1);
    adj[p] = pr >> sh;
  }
}

// ---------------- Embedding: GEMM1 fp32 (K=F), GEMM2 on MFMA (K=64, bf16) ----------------
// out = relu(relu(pn(x)@W1+b1)@W2+b2) [+ bi*bW], 64-node tile per block

template <int F>
__global__ __launch_bounds__(256) void embed_mm(
    const float* __restrict__ x, const float* __restrict__ shift,
    const float* __restrict__ scale, const float* __restrict__ W1,
    const float* __restrict__ b1, const float* __restrict__ W2,
    const float* __restrict__ b2, const float* __restrict__ bi,
    const float* __restrict__ bW, u16* __restrict__ outbf, int n) {
  __shared__ float Xs[F * 68];    // transposed: Xs[k][row], pitch 68
  __shared__ float W1s[F * 68];   // W1'[k][j] = scale_k * W1[k][j], pitch 68
  __shared__ u16 Hs[64][72];      // H bf16
  __shared__ u16 W2s[64][72];     // W2^T bf16: W2s[n][k]
  __shared__ float b1s[64], b2s[64], bWs[64], bis[64];
  int t = threadIdx.x;
  int v0 = blockIdx.x * 64;

  // stage W2^T bf16 (coalesced 256B global reads, packed b128 LDS writes)
  int sn = t & 63;
  int kq = t >> 6;
  {
    unsigned pk[8];
#pragma unroll
    for (int i = 0; i < 8; ++i) {
      float w0 = W2[(size_t)(kq * 16 + 2 * i) * 64 + sn];
      float w1 = W2[(size_t)(kq * 16 + 2 * i + 1) * 64 + sn];
      pk[i] = pack_bf2(w0, w1);
    }
    *(uint4*)&W2s[sn][kq * 16] = make_uint4(pk[0], pk[1], pk[2], pk[3]);
    *(uint4*)&W2s[sn][kq * 16 + 8] = make_uint4(pk[4], pk[5], pk[6], pk[7]);
  }
  // stage W1' (scale folded)
  for (int i = t; i < F * 64; i += 256) {
    int k = i >> 6, j = i & 63;
    W1s[k * 68 + j] = W1[i] * scale[k];
  }
  // biases
  if (t < 64) {
    float acc = b1[t];
#pragma unroll
    for (int k = 0; k < F; ++k) acc += shift[k] * scale[k] * W1[k * 64 + t];
    b1s[t] = acc;
    b2s[t] = b2[t];
    bWs[t] = bW ? bW[t] : 0.f;
    bis[t] = (bi && v0 + t < n) ? bi[v0 + t] : 0.f;
  }
  // stage X transposed (zero-fill rows >= n)
  for (int i = t; i < 64 * F; i += 256) {
    int row = i / F, k = i - row * F;
    int v = v0 + row;
    Xs[k * 68 + row] = (v < n) ? x[(size_t)v * F + k] : 0.f;
  }
  __syncthreads();

  // GEMM1 fp32: H = relu(X @ W1' + b1'), thread tile 4x4
  int jt = t & 15;
  int vt = t >> 4;
  float c[4][4] = {};
#pragma unroll
  for (int k = 0; k < F; ++k) {
    float4 xv = *(const float4*)&Xs[k * 68 + vt * 4];
    float4 wv = *(const float4*)&W1s[k * 68 + jt * 4];
    c[0][0] += xv.x * wv.x; c[0][1] += xv.x * wv.y; c[0][2] += xv.x * wv.z; c[0][3] += xv.x * wv.w;
    c[1][0] += xv.y * wv.x; c[1][1] += xv.y * wv.y; c[1][2] += xv.y * wv.z; c[1][3] += xv.y * wv.w;
    c[2][0] += xv.z * wv.x; c[2][1] += xv.z * wv.y; c[2][2] += xv.z * wv.z; c[2][3] += xv.z * wv.w;
    c[3][0] += xv.w * wv.x; c[3][1] += xv.w * wv.y; c[3][2] += xv.w * wv.z; c[3][3] += xv.w * wv.w;
  }
#pragma unroll
  for (int i = 0; i < 4; ++i) {
    float h0 = fmaxf(c[i][0] + b1s[jt * 4 + 0], 0.f);
    float h1 = fmaxf(c[i][1] + b1s[jt * 4 + 1], 0.f);
    float h2 = fmaxf(c[i][2] + b1s[jt * 4 + 2], 0.f);
    float h3 = fmaxf(c[i][3] + b1s[jt * 4 + 3], 0.f);
    *(uint2*)&Hs[vt * 4 + i][jt * 4] = make_uint2(pack_bf2(h0, h1), pack_bf2(h2, h3));
  }
  __syncthreads();

  // GEMM2 MFMA: out = relu(H @ W2 + b2) + bi*bW
  int l = t & 63;
  int w = t >> 6;
  int m0 = w * 16;
  int rA = m0 + (l & 15);
  int koffA = (l >> 4) * 8;
  f32x4 acc[4] = {};
  {
    bf16x8 a0 = *(const bf16x8*)&Hs[rA][koffA];
    bf16x8 a1 = *(const bf16x8*)&Hs[rA][32 + koffA];
#pragma unroll
    for (int cb = 0; cb < 4; ++cb) {
      int nB = cb * 16 + (l & 15);
      bf16x8 b0 = *(const bf16x8*)&W2s[nB][koffA];
      bf16x8 bb1 = *(const bf16x8*)&W2s[nB][32 + koffA];
      acc[cb] = __builtin_amdgcn_mfma_f32_16x16x32_bf16(a0, b0, acc[cb], 0, 0, 0);
      acc[cb] = __builtin_amdgcn_mfma_f32_16x16x32_bf16(a1, bb1, acc[cb], 0, 0, 0);
    }
  }
#pragma unroll
  for (int cb = 0; cb < 4; ++cb) {
    int colc = cb * 16 + (l & 15);
    float bias = b2s[colc];
    float bwv = bWs[colc];
#pragma unroll
    for (int j = 0; j < 4; ++j) {
      int rowc = m0 + (l >> 4) * 4 + j;
      int v = v0 + rowc;
      if (v < n) {
        float val = fmaxf(acc[cb][j] + bias, 0.f) + bis[rowc] * bwv;
        outbf[(size_t)v * 64 + colc] = f2bf(val);
      }
    }
  }
}

// ---------------- Fused SAGE with MFMA dense phase ----------------
// out = relu(mean(srcbf[neigh]) @ Wl + bl + dstbf @ Wr), 64-node tile per block

template <int OUTBF>
__global__ __launch_bounds__(256) void sage_mfma(
    const uint2* __restrict__ srcbf, const uint2* __restrict__ dstbf,
    const int* __restrict__ off, const int* __restrict__ adj,
    const float* __restrict__ Wl, const float* __restrict__ bl,
    const float* __restrict__ Wr, float* __restrict__ outf,
    u16* __restrict__ outbf, int n) {
  __shared__ u16 Hs[64][72];
  __shared__ u16 Ws[64][72];  // W^T: Ws[n][k]
  __shared__ float bls[64];
  int t = threadIdx.x;
  int v0 = blockIdx.x * 64;
  if (t < 64) bls[t] = bl[t];

  // stage Wl^T as bf16
  int sn = t & 63;
  int kq = t >> 6;
  {
    unsigned pk[8];
#pragma unroll
    for (int i = 0; i < 8; ++i) {
      float w0 = Wl[(size_t)(kq * 16 + 2 * i) * 64 + sn];
      float w1 = Wl[(size_t)(kq * 16 + 2 * i + 1) * 64 + sn];
      pk[i] = pack_bf2(w0, w1);
    }
    *(uint4*)&Ws[sn][kq * 16] = make_uint4(pk[0], pk[1], pk[2], pk[3]);
    *(uint4*)&Ws[sn][kq * 16 + 8] = make_uint4(pk[4], pk[5], pk[6], pk[7]);
  }

  // Phase A: gather-mean into Hs (bf16 rows, 16 lanes/node, 4 loads in flight)
  int lane = t & 15;
  int g = t >> 4;
#pragma unroll
  for (int grp = 0; grp < 4; ++grp) {
    int r = grp * 16 + g;
    int v = v0 + r;
    float ax = 0.f, ay = 0.f, az = 0.f, aw = 0.f;
    if (v < n) {
      int s0 = off[v], s1 = off[v + 1];
      int i = s0;
      for (; i + 4 <= s1; i += 4) {
        int u0 = adj[i], u1 = adj[i + 1], u2 = adj[i + 2], u3 = adj[i + 3];
        uint2 a0 = srcbf[(size_t)u0 * 16 + lane];
        uint2 a1 = srcbf[(size_t)u1 * 16 + lane];
        uint2 a2 = srcbf[(size_t)u2 * 16 + lane];
        uint2 a3 = srcbf[(size_t)u3 * 16 + lane];
        ax += (b2f_lo(a0.x) + b2f_lo(a1.x)) + (b2f_lo(a2.x) + b2f_lo(a3.x));
        ay += (b2f_hi(a0.x) + b2f_hi(a1.x)) + (b2f_hi(a2.x) + b2f_hi(a3.x));
        az += (b2f_lo(a0.y) + b2f_lo(a1.y)) + (b2f_lo(a2.y) + b2f_lo(a3.y));
        aw += (b2f_hi(a0.y) + b2f_hi(a1.y)) + (b2f_hi(a2.y) + b2f_hi(a3.y));
      }
      if (i + 2 <= s1) {
        int u0 = adj[i], u1 = adj[i + 1];
        uint2 a0 = srcbf[(size_t)u0 * 16 + lane];
        uint2 a1 = srcbf[(size_t)u1 * 16 + lane];
        ax += b2f_lo(a0.x) + b2f_lo(a1.x);
        ay += b2f_hi(a0.x) + b2f_hi(a1.x);
        az += b2f_lo(a0.y) + b2f_lo(a1.y);
        aw += b2f_hi(a0.y) + b2f_hi(a1.y);
        i += 2;
      }
      if (i < s1) {
        uint2 a = srcbf[(size_t)adj[i] * 16 + lane];
        ax += b2f_lo(a.x);
        ay += b2f_hi(a.x);
        az += b2f_lo(a.y);
        aw += b2f_hi(a.y);
      }
      int deg = s1 - s0;
      float inv = (deg > 0) ? 1.f / (float)deg : 0.f;
      ax *= inv;
      ay *= inv;
      az *= inv;
      aw *= inv;
    }
    *(uint2*)&Hs[r][lane * 4] = make_uint2(pack_bf2(ax, ay), pack_bf2(az, aw));
  }
  __syncthreads();

  // MFMA phase 1: acc = mean @ Wl
  int l = t & 63;
  int w = t >> 6;
  int m0 = w * 16;
  int rA = m0 + (l & 15);
  int koffA = (l >> 4) * 8;
  f32x4 acc[4] = {};
  {
    bf16x8 a0 = *(const bf16x8*)&Hs[rA][koffA];
    bf16x8 a1 = *(const bf16x8*)&Hs[rA][32 + koffA];
#pragma unroll
    for (int cb = 0; cb < 4; ++cb) {
      int nB = cb * 16 + (l & 15);
      bf16x8 b0 = *(const bf16x8*)&Ws[nB][koffA];
      bf16x8 b1 = *(const bf16x8*)&Ws[nB][32 + koffA];
      acc[cb] = __builtin_amdgcn_mfma_f32_16x16x32_bf16(a0, b0, acc[cb], 0, 0, 0);
      acc[cb] = __builtin_amdgcn_mfma_f32_16x16x32_bf16(a1, b1, acc[cb], 0, 0, 0);
    }
  }
  __syncthreads();

  // restage: Hs <- dst tile (bf16 copy), Ws <- Wr^T
#pragma unroll
  for (int r4 = 0; r4 < 4; ++r4) {
    int idx = t + 256 * r4;
    int rowi = idx >> 4, f4 = idx & 15;
    int v = v0 + rowi;
    uint2 val = (v < n) ? dstbf[(size_t)v * 16 + f4] : make_uint2(0u, 0u);
    *(uint2*)&Hs[rowi][f4 * 4] = val;
  }
  {
    unsigned pk[8];
#pragma unroll
    for (int i = 0; i < 8; ++i) {
      float w0 = Wr[(size_t)(kq * 16 + 2 * i) * 64 + sn];
      float w1 = Wr[(size_t)(kq * 16 + 2 * i + 1) * 64 + sn];
      pk[i] = pack_bf2(w0, w1);
    }
    *(uint4*)&Ws[sn][kq * 16] = make_uint4(pk[0], pk[1], pk[2], pk[3]);
    *(uint4*)&Ws[sn][kq * 16 + 8] = make_uint4(pk[4], pk[5], pk[6], pk[7]);
  }
  __syncthreads();

  // MFMA phase 2: acc += dst @ Wr
  {
    bf16x8 a0 = *(const bf16x8*)&Hs[rA][koffA];
    bf16x8 a1 = *(const bf16x8*)&Hs[rA][32 + koffA];
#pragma unroll
    for (int cb = 0; cb < 4; ++cb) {
      int nB = cb * 16 + (l & 15);
      bf16x8 b0 = *(const bf16x8*)&Ws[nB][koffA];
      bf16x8 b1 = *(const bf16x8*)&Ws[nB][32 + koffA];
      acc[cb] = __builtin_amdgcn_mfma_f32_16x16x32_bf16(a0, b0, acc[cb], 0, 0, 0);
      acc[cb] = __builtin_amdgcn_mfma_f32_16x16x32_bf16(a1, b1, acc[cb], 0, 0, 0);
    }
  }

  // epilogue: bias + relu + store (D: col=l&15 within cb*16, row=(l>>4)*4+j)
#pragma unroll
  for (int cb = 0; cb < 4; ++cb) {
    int colc = cb * 16 + (l & 15);
    float bias = bls[colc];
#pragma unroll
    for (int j = 0; j < 4; ++j) {
      int rowc = m0 + (l >> 4) * 4 + j;
      int v = v0 + rowc;
      if (v < n) {
        float val = fmaxf(acc[cb][j] + bias, 0.f);
        if (OUTBF) {
          outbf[(size_t)v * 64 + colc] = f2bf(val);
        } else {
          outf[(size_t)v * 64 + colc] = val;
        }
      }
    }
  }
}

// ---------------- host ----------------

extern "C" void kernel_launch(void* const* d_in, const int* in_sizes, int n_in,
                              void* d_out, int out_size, void* d_ws, size_t ws_size,
                              hipStream_t stream) {
  const float* cons_x = (const float*)d_in[0];
  const float* var_x  = (const float*)d_in[1];
  const int*   eidx   = (const int*)d_in[2];
  const float* bi     = (const float*)d_in[4];
  const float* c_sh   = (const float*)d_in[5];
  const float* c_sc   = (const float*)d_in[6];
  const float* v_sh   = (const float*)d_in[7];
  const float* v_sc   = (const float*)d_in[8];
  const float* cW1 = (const float*)d_in[11];
  const float* cb1 = (const float*)d_in[12];
  const float* cW2 = (const float*)d_in[13];
  const float* cb2 = (const float*)d_in[14];
  const float* vW1 = (const float*)d_in[15];
  const float* vb1 = (const float*)d_in[16];
  const float* vW2 = (const float*)d_in[17];
  const float* vb2 = (const float*)d_in[18];
  const float* bW  = (const float*)d_in[19];
  const float* Wl_cv = (const float*)d_in[20];
  const float* bl_cv = (const float*)d_in[21];
  const float* Wr_cv = (const float*)d_in[22];
  const float* Wl_vc = (const float*)d_in[23];
  const float* bl_vc = (const float*)d_in[24];
  const float* Wr_vc = (const float*)d_in[25];

  const int* row = eidx;           // [E] constraint index per edge
  const int* col = eidx + N_EDGE;  // [E] variable index per edge

  char* ws = (char*)d_ws;
  size_t o = 0;
  auto alloc = [&](size_t bytes) {
    char* p = ws + o;
    o = (o + bytes + 255) & ~(size_t)255;
    return p;
  };
  int* off    = (int*)alloc((N_TOT + 1) * sizeof(int));
  int* adj    = (int*)alloc((size_t)2 * N_EDGE * sizeof(int));
  int* pairV  = (int*)alloc((size_t)NBV * CAPV * sizeof(int));
  int* pairC  = (int*)alloc((size_t)NBC * CAPC * sizeof(int));
  int* gcurV  = (int*)alloc(256 * sizeof(int));
  int* gcurC  = (int*)alloc(256 * sizeof(int));
  int* ebaseV = (int*)alloc(256 * sizeof(int));
  int* ebaseC = (int*)alloc(256 * sizeof(int));
  uint2* consEbf = (uint2*)alloc((size_t)N_CONS * EMB * 2);
  uint2* varEbf  = (uint2*)alloc((size_t)N_VAR * EMB * 2);
  uint2* cons1bf = (uint2*)alloc((size_t)N_CONS * EMB * 2);
  uint2* var1bf  = (uint2*)alloc((size_t)N_VAR * EMB * 2);
  float* var_out = (float*)d_out;

  csr_init<<<1, 256, 0, stream>>>(gcurV, gcurC, off);
  bucket_scatter<<<512, 256, 0, stream>>>(row, col, gcurV, gcurC, pairV, pairC);
  bucket_scan<<<1, 256, 0, stream>>>(gcurV, gcurC, ebaseV, ebaseC);
  local_csr<<<NBV + NBC, 256, 0, stream>>>(pairV, pairC, ebaseV, ebaseC, off, adj);

  embed_mm<5><<<(N_CONS + 63) / 64, 256, 0, stream>>>(
      cons_x, c_sh, c_sc, cW1, cb1, cW2, cb2, nullptr, nullptr, (u16*)consEbf,
      N_CONS);
  embed_mm<19><<<(N_VAR + 63) / 64, 256, 0, stream>>>(
      var_x, v_sh, v_sc, vW1, vb1, vW2, vb2, bi, bW, (u16*)varEbf, N_VAR);

  // layer 0, var side: var1bf = relu(mean_cons @ Wl_cv + bl + varE @ Wr_cv)
  sage_mfma<1><<<(N_VAR + 63) / 64, 256, 0, stream>>>(
      consEbf, varEbf, off, adj, Wl_cv, bl_cv, Wr_cv, nullptr, (u16*)var1bf,
      N_VAR);
  // layer 0, cons side -> bf16 (gather source of layer 1)
  sage_mfma<1><<<(N_CONS + 63) / 64, 256, 0, stream>>>(
      varEbf, consEbf, off + N_VAR, adj, Wl_vc, bl_vc, Wr_vc, nullptr,
      (u16*)cons1bf, N_CONS);
  // layer 1, var side only -> fp32 d_out
  sage_mfma<0><<<(N_VAR + 63) / 64, 256, 0, stream>>>(
      cons1bf, var1bf, off, adj, Wl_cv + 4096, bl_cv + 64, Wr_cv + 4096,
      var_out, nullptr, N_VAR);
}

// Round 10
// 258.864 us; speedup vs baseline: 14.0751x; 1.0855x over previous
//
#include <hip/hip_runtime.h>

#define N_CONS 100000
#define N_VAR  200000
#define N_TOT  (N_CONS + N_VAR)
#define N_EDGE 2000000
#define EMB 64

#define VSH 10
#define NBV 196    // ceil(200000/1024)
#define CAPV 12288
#define CSH 9
#define NBC 196    // ceil(100000/512)
#define CAPC 12288
#define CAPAV (CAPV + 3 * 1024)  // padded adj capacity per var bucket
#define CAPAC (CAPC + 3 * 512)   // padded adj capacity per cons bucket
#define NB_VAR ((N_VAR + 63) / 64)    // 3125
#define NB_CONS ((N_CONS + 63) / 64)  // 1563

typedef unsigned short u16;
typedef __attribute__((ext_vector_type(8))) short bf16x8;
typedef __attribute__((ext_vector_type(4))) float f32x4;

// ---------------- bf16 helpers ----------------

__device__ __forceinline__ float b2f_lo(unsigned u) {
  union { unsigned i; float f; } c;
  c.i = u << 16;
  return c.f;
}
__device__ __forceinline__ float b2f_hi(unsigned u) {
  union { unsigned i; float f; } c;
  c.i = u & 0xFFFF0000u;
  return c.f;
}
__device__ __forceinline__ unsigned pack_bf2(float a, float b) {
  unsigned ua = __float_as_uint(a), ub = __float_as_uint(b);
  unsigned ra = (ua + 0x7FFFu + ((ua >> 16) & 1u)) >> 16;
  unsigned rb = (ub + 0x7FFFu + ((ub >> 16) & 1u)) >> 16;
  return ra | (rb << 16);
}
__device__ __forceinline__ u16 f2bf(float a) {
  unsigned ua = __float_as_uint(a);
  return (u16)((ua + 0x7FFFu + ((ua >> 16) & 1u)) >> 16);
}

// ---------------- CSR build: bucketed counting sort ----------------

// init bucket cursors + zero rows of gather tables (padding target rows)
__global__ __launch_bounds__(256) void csr_init(int* __restrict__ gcurV,
                                                int* __restrict__ gcurC,
                                                uint2* __restrict__ consEbf,
                                                uint2* __restrict__ varEbf,
                                                uint2* __restrict__ cons1bf) {
  int t = threadIdx.x;
  if (t < NBV) gcurV[t] = t * CAPV;
  if (t < NBC) gcurC[t] = t * CAPC;
  if (t < 16) consEbf[(size_t)N_CONS * 16 + t] = make_uint2(0u, 0u);
  else if (t < 32) varEbf[(size_t)N_VAR * 16 + (t - 16)] = make_uint2(0u, 0u);
  else if (t < 48) cons1bf[(size_t)N_CONS * 16 + (t - 32)] = make_uint2(0u, 0u);
}

__global__ __launch_bounds__(256) void bucket_scatter(
    const int* __restrict__ row, const int* __restrict__ col,
    int* __restrict__ gcurV, int* __restrict__ gcurC,
    int* __restrict__ pairV, int* __restrict__ pairC) {
  __shared__ int hV[NBV];
  __shared__ int hC[NBC];
  int tid = threadIdx.x;
  int chunk = (N_EDGE + gridDim.x - 1) / gridDim.x;
  int lo = blockIdx.x * chunk;
  int hi = min(N_EDGE, lo + chunk);
  for (int i = tid; i < NBV; i += 256) hV[i] = 0;
  for (int i = tid; i < NBC; i += 256) hC[i] = 0;
  __syncthreads();
  for (int e = lo + tid; e < hi; e += 256) {
    atomicAdd(&hV[col[e] >> VSH], 1);
    atomicAdd(&hC[row[e] >> CSH], 1);
  }
  __syncthreads();
  for (int i = tid; i < NBV; i += 256) {
    int c = hV[i];
    hV[i] = c ? atomicAdd(&gcurV[i], c) : 0;
  }
  for (int i = tid; i < NBC; i += 256) {
    int c = hC[i];
    hC[i] = c ? atomicAdd(&gcurC[i], c) : 0;
  }
  __syncthreads();
  for (int e = lo + tid; e < hi; e += 256) {
    int r = row[e], c = col[e];
    int p = atomicAdd(&hV[c >> VSH], 1);
    pairV[p] = (r << VSH) | (c & ((1 << VSH) - 1));
    int q = atomicAdd(&hC[r >> CSH], 1);
    pairC[q] = (c << CSH) | (r & ((1 << CSH) - 1));
  }
}

// Per bucket: per-node counts, padded prefix (x4), write off/deg, scatter adj,
// fill pad slots with the source table's zero row. 1024 threads/block.
__global__ __launch_bounds__(1024) void local_csr(
    const int* __restrict__ pairV, const int* __restrict__ pairC,
    const int* __restrict__ gcurV, const int* __restrict__ gcurC,
    int* __restrict__ off, int* __restrict__ deg, int* __restrict__ adj) {
  __shared__ int cnt[1024];
  __shared__ int s[1024];
  __shared__ int cur[1024];
  int tid = threadIdx.x;
  int b = blockIdx.x;
  const int* pairs;
  int m, obase, nn, sh, zrow;
  int* offp;
  int* degp;
  if (b < NBV) {
    pairs = pairV + (size_t)b * CAPV;
    m = gcurV[b] - b * CAPV;
    obase = b * CAPAV;
    nn = min(1024, N_VAR - (b << 10));
    sh = VSH;
    zrow = N_CONS;  // var-dst buckets gather cons sources
    offp = off + (b << 10);
    degp = deg + (b << 10);
  } else {
    int bb = b - NBV;
    pairs = pairC + (size_t)bb * CAPC;
    m = gcurC[bb] - bb * CAPC;
    obase = NBV * CAPAV + bb * CAPAC;
    nn = min(512, N_CONS - (bb << 9));
    sh = CSH;
    zrow = N_VAR;  // cons-dst buckets gather var sources
    offp = off + N_VAR + (bb << 9);
    degp = deg + N_VAR + (bb << 9);
  }
  int mask = (1 << sh) - 1;
  cnt[tid] = 0;
  __syncthreads();
  for (int k = tid; k < m; k += 1024) atomicAdd(&cnt[pairs[k] & mask], 1);
  __syncthreads();
  int c = cnt[tid];
  int pc = (c + 3) & ~3;
  s[tid] = pc;
  __syncthreads();
  for (int d1 = 1; d1 < 1024; d1 <<= 1) {
    int x = (tid >= d1) ? s[tid - d1] : 0;
    __syncthreads();
    s[tid] += x;
    __syncthreads();
  }
  int start = obase + s[tid] - pc;
  cur[tid] = start;
  if (tid < nn) {
    offp[tid] = start;
    degp[tid] = c;
  }
  __syncthreads();
  for (int k = tid; k < m; k += 1024) {
    int pr = pairs[k];
    int p = atomicAdd(&cur[pr & mask], 1);
    adj[p] = pr >> sh;
  }
  for (int q = c; q < pc; ++q) adj[start + q] = zrow;  // pad (<=3 per node)
}

// ---------------- Embedding: GEMM1 fp32 (K=F), GEMM2 on MFMA (K=64, bf16) ----------------

template <int F>
__global__ __launch_bounds__(256) void embed_mm(
    const float* __restrict__ x, const float* __restrict__ shift,
    const float* __restrict__ scale, const float* __restrict__ W1,
    const float* __restrict__ b1, const float* __restrict__ W2,
    const float* __restrict__ b2, const float* __restrict__ bi,
    const float* __restrict__ bW, u16* __restrict__ outbf, int n) {
  __shared__ float Xs[F * 68];
  __shared__ float W1s[F * 68];
  __shared__ u16 Hs[64][72];
  __shared__ u16 W2s[64][72];
  __shared__ float b1s[64], b2s[64], bWs[64], bis[64];
  int t = threadIdx.x;
  int v0 = blockIdx.x * 64;

  int sn = t & 63;
  int kq = t >> 6;
  {
    unsigned pk[8];
#pragma unroll
    for (int i = 0; i < 8; ++i) {
      float w0 = W2[(size_t)(kq * 16 + 2 * i) * 64 + sn];
      float w1 = W2[(size_t)(kq * 16 + 2 * i + 1) * 64 + sn];
      pk[i] = pack_bf2(w0, w1);
    }
    *(uint4*)&W2s[sn][kq * 16] = make_uint4(pk[0], pk[1], pk[2], pk[3]);
    *(uint4*)&W2s[sn][kq * 16 + 8] = make_uint4(pk[4], pk[5], pk[6], pk[7]);
  }
  for (int i = t; i < F * 64; i += 256) {
    int k = i >> 6, j = i & 63;
    W1s[k * 68 + j] = W1[i] * scale[k];
  }
  if (t < 64) {
    float acc = b1[t];
#pragma unroll
    for (int k = 0; k < F; ++k) acc += shift[k] * scale[k] * W1[k * 64 + t];
    b1s[t] = acc;
    b2s[t] = b2[t];
    bWs[t] = bW ? bW[t] : 0.f;
    bis[t] = (bi && v0 + t < n) ? bi[v0 + t] : 0.f;
  }
  for (int i = t; i < 64 * F; i += 256) {
    int row = i / F, k = i - row * F;
    int v = v0 + row;
    Xs[k * 68 + row] = (v < n) ? x[(size_t)v * F + k] : 0.f;
  }
  __syncthreads();

  int jt = t & 15;
  int vt = t >> 4;
  float c[4][4] = {};
#pragma unroll
  for (int k = 0; k < F; ++k) {
    float4 xv = *(const float4*)&Xs[k * 68 + vt * 4];
    float4 wv = *(const float4*)&W1s[k * 68 + jt * 4];
    c[0][0] += xv.x * wv.x; c[0][1] += xv.x * wv.y; c[0][2] += xv.x * wv.z; c[0][3] += xv.x * wv.w;
    c[1][0] += xv.y * wv.x; c[1][1] += xv.y * wv.y; c[1][2] += xv.y * wv.z; c[1][3] += xv.y * wv.w;
    c[2][0] += xv.z * wv.x; c[2][1] += xv.z * wv.y; c[2][2] += xv.z * wv.z; c[2][3] += xv.z * wv.w;
    c[3][0] += xv.w * wv.x; c[3][1] += xv.w * wv.y; c[3][2] += xv.w * wv.z; c[3][3] += xv.w * wv.w;
  }
#pragma unroll
  for (int i = 0; i < 4; ++i) {
    float h0 = fmaxf(c[i][0] + b1s[jt * 4 + 0], 0.f);
    float h1 = fmaxf(c[i][1] + b1s[jt * 4 + 1], 0.f);
    float h2 = fmaxf(c[i][2] + b1s[jt * 4 + 2], 0.f);
    float h3 = fmaxf(c[i][3] + b1s[jt * 4 + 3], 0.f);
    *(uint2*)&Hs[vt * 4 + i][jt * 4] = make_uint2(pack_bf2(h0, h1), pack_bf2(h2, h3));
  }
  __syncthreads();

  int l = t & 63;
  int w = t >> 6;
  int m0 = w * 16;
  int rA = m0 + (l & 15);
  int koffA = (l >> 4) * 8;
  f32x4 acc[4] = {};
  {
    bf16x8 a0 = *(const bf16x8*)&Hs[rA][koffA];
    bf16x8 a1 = *(const bf16x8*)&Hs[rA][32 + koffA];
#pragma unroll
    for (int cb = 0; cb < 4; ++cb) {
      int nB = cb * 16 + (l & 15);
      bf16x8 b0 = *(const bf16x8*)&W2s[nB][koffA];
      bf16x8 bb1 = *(const bf16x8*)&W2s[nB][32 + koffA];
      acc[cb] = __builtin_amdgcn_mfma_f32_16x16x32_bf16(a0, b0, acc[cb], 0, 0, 0);
      acc[cb] = __builtin_amdgcn_mfma_f32_16x16x32_bf16(a1, bb1, acc[cb], 0, 0, 0);
    }
  }
#pragma unroll
  for (int cb = 0; cb < 4; ++cb) {
    int colc = cb * 16 + (l & 15);
    float bias = b2s[colc];
    float bwv = bWs[colc];
#pragma unroll
    for (int j = 0; j < 4; ++j) {
      int rowc = m0 + (l >> 4) * 4 + j;
      int v = v0 + rowc;
      if (v < n) {
        float val = fmaxf(acc[cb][j] + bias, 0.f) + bis[rowc] * bwv;
        outbf[(size_t)v * 64 + colc] = f2bf(val);
      }
    }
  }
}

// ---------------- Fused SAGE body (MFMA dense, padded gather) ----------------

template <int OUTBF>
__device__ __forceinline__ void sage_body(
    const uint2* __restrict__ srcbf, const uint2* __restrict__ dstbf,
    const int* __restrict__ off, const int* __restrict__ deg,
    const int* __restrict__ adj, const float* __restrict__ Wl,
    const float* __restrict__ bl, const float* __restrict__ Wr,
    float* __restrict__ outf, u16* __restrict__ outbf, int n, int v0,
    u16 (*Hs)[72], u16 (*Ws)[72], float* bls) {
  int t = threadIdx.x;
  if (t < 64) bls[t] = bl[t];

  int sn = t & 63;
  int kq = t >> 6;
  {
    unsigned pk[8];
#pragma unroll
    for (int i = 0; i < 8; ++i) {
      float w0 = Wl[(size_t)(kq * 16 + 2 * i) * 64 + sn];
      float w1 = Wl[(size_t)(kq * 16 + 2 * i + 1) * 64 + sn];
      pk[i] = pack_bf2(w0, w1);
    }
    *(uint4*)&Ws[sn][kq * 16] = make_uint4(pk[0], pk[1], pk[2], pk[3]);
    *(uint4*)&Ws[sn][kq * 16 + 8] = make_uint4(pk[4], pk[5], pk[6], pk[7]);
  }

  // gather-mean: padded uniform 4-deep loop (pad entries hit the zero row)
  int lane = t & 15;
  int g = t >> 4;
#pragma unroll
  for (int grp = 0; grp < 4; ++grp) {
    int r = grp * 16 + g;
    int v = v0 + r;
    float ax = 0.f, ay = 0.f, az = 0.f, aw = 0.f;
    if (v < n) {
      int s0 = off[v];
      int d = deg[v];
      int e4 = s0 + ((d + 3) & ~3);
      for (int i = s0; i < e4; i += 4) {
        int u0 = adj[i], u1 = adj[i + 1], u2 = adj[i + 2], u3 = adj[i + 3];
        uint2 a0 = srcbf[(size_t)u0 * 16 + lane];
        uint2 a1 = srcbf[(size_t)u1 * 16 + lane];
        uint2 a2 = srcbf[(size_t)u2 * 16 + lane];
        uint2 a3 = srcbf[(size_t)u3 * 16 + lane];
        ax += (b2f_lo(a0.x) + b2f_lo(a1.x)) + (b2f_lo(a2.x) + b2f_lo(a3.x));
        ay += (b2f_hi(a0.x) + b2f_hi(a1.x)) + (b2f_hi(a2.x) + b2f_hi(a3.x));
        az += (b2f_lo(a0.y) + b2f_lo(a1.y)) + (b2f_lo(a2.y) + b2f_lo(a3.y));
        aw += (b2f_hi(a0.y) + b2f_hi(a1.y)) + (b2f_hi(a2.y) + b2f_hi(a3.y));
      }
      float inv = (d > 0) ? 1.f / (float)d : 0.f;
      ax *= inv;
      ay *= inv;
      az *= inv;
      aw *= inv;
    }
    *(uint2*)&Hs[r][lane * 4] = make_uint2(pack_bf2(ax, ay), pack_bf2(az, aw));
  }
  __syncthreads();

  int l = t & 63;
  int w = t >> 6;
  int m0 = w * 16;
  int rA = m0 + (l & 15);
  int koffA = (l >> 4) * 8;
  f32x4 acc[4] = {};
  {
    bf16x8 a0 = *(const bf16x8*)&Hs[rA][koffA];
    bf16x8 a1 = *(const bf16x8*)&Hs[rA][32 + koffA];
#pragma unroll
    for (int cb = 0; cb < 4; ++cb) {
      int nB = cb * 16 + (l & 15);
      bf16x8 b0 = *(const bf16x8*)&Ws[nB][koffA];
      bf16x8 b1 = *(const bf16x8*)&Ws[nB][32 + koffA];
      acc[cb] = __builtin_amdgcn_mfma_f32_16x16x32_bf16(a0, b0, acc[cb], 0, 0, 0);
      acc[cb] = __builtin_amdgcn_mfma_f32_16x16x32_bf16(a1, b1, acc[cb], 0, 0, 0);
    }
  }
  __syncthreads();

#pragma unroll
  for (int r4 = 0; r4 < 4; ++r4) {
    int idx = t + 256 * r4;
    int rowi = idx >> 4, f4 = idx & 15;
    int v = v0 + rowi;
    uint2 val = (v < n) ? dstbf[(size_t)v * 16 + f4] : make_uint2(0u, 0u);
    *(uint2*)&Hs[rowi][f4 * 4] = val;
  }
  {
    unsigned pk[8];
#pragma unroll
    for (int i = 0; i < 8; ++i) {
      float w0 = Wr[(size_t)(kq * 16 + 2 * i) * 64 + sn];
      float w1 = Wr[(size_t)(kq * 16 + 2 * i + 1) * 64 + sn];
      pk[i] = pack_bf2(w0, w1);
    }
    *(uint4*)&Ws[sn][kq * 16] = make_uint4(pk[0], pk[1], pk[2], pk[3]);
    *(uint4*)&Ws[sn][kq * 16 + 8] = make_uint4(pk[4], pk[5], pk[6], pk[7]);
  }
  __syncthreads();

  {
    bf16x8 a0 = *(const bf16x8*)&Hs[rA][koffA];
    bf16x8 a1 = *(const bf16x8*)&Hs[rA][32 + koffA];
#pragma unroll
    for (int cb = 0; cb < 4; ++cb) {
      int nB = cb * 16 + (l & 15);
      bf16x8 b0 = *(const bf16x8*)&Ws[nB][koffA];
      bf16x8 b1 = *(const bf16x8*)&Ws[nB][32 + koffA];
      acc[cb] = __builtin_amdgcn_mfma_f32_16x16x32_bf16(a0, b0, acc[cb], 0, 0, 0);
      acc[cb] = __builtin_amdgcn_mfma_f32_16x16x32_bf16(a1, b1, acc[cb], 0, 0, 0);
    }
  }

#pragma unroll
  for (int cb = 0; cb < 4; ++cb) {
    int colc = cb * 16 + (l & 15);
    float bias = bls[colc];
#pragma unroll
    for (int j = 0; j < 4; ++j) {
      int rowc = m0 + (l >> 4) * 4 + j;
      int v = v0 + rowc;
      if (v < n) {
        float val = fmaxf(acc[cb][j] + bias, 0.f);
        if (OUTBF) {
          outbf[(size_t)v * 64 + colc] = f2bf(val);
        } else {
          outf[(size_t)v * 64 + colc] = val;
        }
      }
    }
  }
}

// layer 0: both directions in one dispatch (independent)
__global__ __launch_bounds__(256) void sage_l0(
    const uint2* __restrict__ consEbf, const uint2* __restrict__ varEbf,
    const int* __restrict__ off, const int* __restrict__ deg,
    const int* __restrict__ adj, const float* __restrict__ Wl_cv,
    const float* __restrict__ bl_cv, const float* __restrict__ Wr_cv,
    const float* __restrict__ Wl_vc, const float* __restrict__ bl_vc,
    const float* __restrict__ Wr_vc, u16* __restrict__ var1bf,
    u16* __restrict__ cons1bf) {
  __shared__ u16 Hs[64][72];
  __shared__ u16 Ws[64][72];
  __shared__ float bls[64];
  int b = blockIdx.x;
  if (b < NB_VAR) {
    sage_body<1>(consEbf, varEbf, off, deg, adj, Wl_cv, bl_cv, Wr_cv, nullptr,
                 var1bf, N_VAR, b * 64, Hs, Ws, bls);
  } else {
    sage_body<1>(varEbf, consEbf, off + N_VAR, deg + N_VAR, adj, Wl_vc, bl_vc,
                 Wr_vc, nullptr, cons1bf, N_CONS, (b - NB_VAR) * 64, Hs, Ws, bls);
  }
}

// layer 1: var side only, fp32 out
__global__ __launch_bounds__(256) void sage_l1(
    const uint2* __restrict__ cons1bf, const uint2* __restrict__ var1bf,
    const int* __restrict__ off, const int* __restrict__ deg,
    const int* __restrict__ adj, const float* __restrict__ Wl,
    const float* __restrict__ bl, const float* __restrict__ Wr,
    float* __restrict__ out) {
  __shared__ u16 Hs[64][72];
  __shared__ u16 Ws[64][72];
  __shared__ float bls[64];
  sage_body<0>(cons1bf, var1bf, off, deg, adj, Wl, bl, Wr, out, nullptr, N_VAR,
               blockIdx.x * 64, Hs, Ws, bls);
}

// ---------------- host ----------------

extern "C" void kernel_launch(void* const* d_in, const int* in_sizes, int n_in,
                              void* d_out, int out_size, void* d_ws, size_t ws_size,
                              hipStream_t stream) {
  const float* cons_x = (const float*)d_in[0];
  const float* var_x  = (const float*)d_in[1];
  const int*   eidx   = (const int*)d_in[2];
  const float* bi     = (const float*)d_in[4];
  const float* c_sh   = (const float*)d_in[5];
  const float* c_sc   = (const float*)d_in[6];
  const float* v_sh   = (const float*)d_in[7];
  const float* v_sc   = (const float*)d_in[8];
  const float* cW1 = (const float*)d_in[11];
  const float* cb1 = (const float*)d_in[12];
  const float* cW2 = (const float*)d_in[13];
  const float* cb2 = (const float*)d_in[14];
  const float* vW1 = (const float*)d_in[15];
  const float* vb1 = (const float*)d_in[16];
  const float* vW2 = (const float*)d_in[17];
  const float* vb2 = (const float*)d_in[18];
  const float* bW  = (const float*)d_in[19];
  const float* Wl_cv = (const float*)d_in[20];
  const float* bl_cv = (const float*)d_in[21];
  const float* Wr_cv = (const float*)d_in[22];
  const float* Wl_vc = (const float*)d_in[23];
  const float* bl_vc = (const float*)d_in[24];
  const float* Wr_vc = (const float*)d_in[25];

  const int* row = eidx;           // [E] constraint index per edge
  const int* col = eidx + N_EDGE;  // [E] variable index per edge

  char* ws = (char*)d_ws;
  size_t o = 0;
  auto alloc = [&](size_t bytes) {
    char* p = ws + o;
    o = (o + bytes + 255) & ~(size_t)255;
    return p;
  };
  int* off   = (int*)alloc((size_t)N_TOT * sizeof(int));
  int* deg   = (int*)alloc((size_t)N_TOT * sizeof(int));
  int* adj   = (int*)alloc(((size_t)NBV * CAPAV + (size_t)NBC * CAPAC) * sizeof(int));
  int* pairV = (int*)alloc((size_t)NBV * CAPV * sizeof(int));
  int* pairC = (int*)alloc((size_t)NBC * CAPC * sizeof(int));
  int* gcurV = (int*)alloc(256 * sizeof(int));
  int* gcurC = (int*)alloc(256 * sizeof(int));
  uint2* consEbf = (uint2*)alloc((size_t)(N_CONS + 1) * EMB * 2);
  uint2* varEbf  = (uint2*)alloc((size_t)(N_VAR + 1) * EMB * 2);
  uint2* cons1bf = (uint2*)alloc((size_t)(N_CONS + 1) * EMB * 2);
  uint2* var1bf  = (uint2*)alloc((size_t)N_VAR * EMB * 2);
  float* var_out = (float*)d_out;

  csr_init<<<1, 256, 0, stream>>>(gcurV, gcurC, consEbf, varEbf, cons1bf);
  bucket_scatter<<<512, 256, 0, stream>>>(row, col, gcurV, gcurC, pairV, pairC);
  local_csr<<<NBV + NBC, 1024, 0, stream>>>(pairV, pairC, gcurV, gcurC, off,
                                            deg, adj);

  embed_mm<5><<<NB_CONS, 256, 0, stream>>>(cons_x, c_sh, c_sc, cW1, cb1, cW2,
                                           cb2, nullptr, nullptr, (u16*)consEbf,
                                           N_CONS);
  embed_mm<19><<<NB_VAR, 256, 0, stream>>>(var_x, v_sh, v_sc, vW1, vb1, vW2,
                                           vb2, bi, bW, (u16*)varEbf, N_VAR);

  // layer 0 (both directions, one dispatch)
  sage_l0<<<NB_VAR + NB_CONS, 256, 0, stream>>>(
      consEbf, varEbf, off, deg, adj, Wl_cv, bl_cv, Wr_cv, Wl_vc, bl_vc, Wr_vc,
      (u16*)var1bf, (u16*)cons1bf);
  // layer 1, var side only -> fp32 d_out
  sage_l1<<<NB_VAR, 256, 0, stream>>>(cons1bf, var1bf, off, deg, adj,
                                      Wl_cv + 4096, bl_cv + 64, Wr_cv + 4096,
                                      var_out);
}

// Round 11
// 248.302 us; speedup vs baseline: 14.6739x; 1.0425x over previous
//
#include <hip/hip_runtime.h>

#define N_CONS 100000
#define N_VAR  200000
#define N_TOT  (N_CONS + N_VAR)
#define N_EDGE 2000000
#define EMB 64

#define VSH 10
#define NBV 196    // ceil(200000/1024)
#define CAPV 12288
#define CSH 9
#define NBC 196    // ceil(100000/512)
#define CAPC 12288
#define CAPAV (CAPV + 3 * 1024)  // padded adj capacity per var bucket
#define CAPAC (CAPC + 3 * 512)   // padded adj capacity per cons bucket
#define NB_VAR ((N_VAR + 63) / 64)    // 3125
#define NB_CONS ((N_CONS + 63) / 64)  // 1563
#define NB_SCAT 512

typedef unsigned short u16;
typedef __attribute__((ext_vector_type(8))) short bf16x8;
typedef __attribute__((ext_vector_type(4))) float f32x4;

// ---------------- bf16 helpers ----------------

__device__ __forceinline__ float b2f_lo(unsigned u) {
  union { unsigned i; float f; } c;
  c.i = u << 16;
  return c.f;
}
__device__ __forceinline__ float b2f_hi(unsigned u) {
  union { unsigned i; float f; } c;
  c.i = u & 0xFFFF0000u;
  return c.f;
}
__device__ __forceinline__ unsigned pack_bf2(float a, float b) {
  unsigned ua = __float_as_uint(a), ub = __float_as_uint(b);
  unsigned ra = (ua + 0x7FFFu + ((ua >> 16) & 1u)) >> 16;
  unsigned rb = (ub + 0x7FFFu + ((ub >> 16) & 1u)) >> 16;
  return ra | (rb << 16);
}
__device__ __forceinline__ u16 f2bf(float a) {
  unsigned ua = __float_as_uint(a);
  return (u16)((ua + 0x7FFFu + ((ua >> 16) & 1u)) >> 16);
}

// ---------------- fused front: bucket_scatter + embed(x2) + pad-row zero ----------------

__device__ __forceinline__ void scatter_body(
    int b, char* smem, const int* __restrict__ row, const int* __restrict__ col,
    int* __restrict__ gcurV, int* __restrict__ gcurC, int* __restrict__ pairV,
    int* __restrict__ pairC) {
  int* hV = (int*)smem;
  int* hC = hV + NBV;
  int tid = threadIdx.x;
  int chunk = (N_EDGE + NB_SCAT - 1) / NB_SCAT;
  int lo = b * chunk;
  int hi = min(N_EDGE, lo + chunk);
  for (int i = tid; i < NBV; i += 256) hV[i] = 0;
  for (int i = tid; i < NBC; i += 256) hC[i] = 0;
  __syncthreads();
  for (int e = lo + tid; e < hi; e += 256) {
    atomicAdd(&hV[col[e] >> VSH], 1);
    atomicAdd(&hC[row[e] >> CSH], 1);
  }
  __syncthreads();
  for (int i = tid; i < NBV; i += 256) {
    int c = hV[i];
    hV[i] = c ? (i * CAPV + atomicAdd(&gcurV[i], c)) : 0;
  }
  for (int i = tid; i < NBC; i += 256) {
    int c = hC[i];
    hC[i] = c ? (i * CAPC + atomicAdd(&gcurC[i], c)) : 0;
  }
  __syncthreads();
  for (int e = lo + tid; e < hi; e += 256) {
    int r = row[e], c = col[e];
    int p = atomicAdd(&hV[c >> VSH], 1);
    pairV[p] = (r << VSH) | (c & ((1 << VSH) - 1));
    int q = atomicAdd(&hC[r >> CSH], 1);
    pairC[q] = (c << CSH) | (r & ((1 << CSH) - 1));
  }
}

// Embedding: GEMM1 fp32 (K=F), GEMM2 on MFMA (K=64, bf16)
template <int F>
__device__ __forceinline__ void embed_body(
    int blk, char* smem, const float* __restrict__ x,
    const float* __restrict__ shift, const float* __restrict__ scale,
    const float* __restrict__ W1, const float* __restrict__ b1,
    const float* __restrict__ W2, const float* __restrict__ b2,
    const float* __restrict__ bi, const float* __restrict__ bW,
    u16* __restrict__ outbf, int n) {
  float* Xs = (float*)smem;                    // [F][68]
  float* W1s = Xs + F * 68;                    // [F][68]
  u16 (*Hs)[72] = (u16(*)[72])(W1s + F * 68);  // [64][72]
  u16 (*W2s)[72] = (u16(*)[72])((char*)Hs + 64 * 72 * 2);
  float* b1s = (float*)((char*)W2s + 64 * 72 * 2);
  float* b2s = b1s + 64;
  float* bWs = b2s + 64;
  float* bis = bWs + 64;
  int t = threadIdx.x;
  int v0 = blk * 64;

  int sn = t & 63;
  int kq = t >> 6;
  {
    unsigned pk[8];
#pragma unroll
    for (int i = 0; i < 8; ++i) {
      float w0 = W2[(size_t)(kq * 16 + 2 * i) * 64 + sn];
      float w1 = W2[(size_t)(kq * 16 + 2 * i + 1) * 64 + sn];
      pk[i] = pack_bf2(w0, w1);
    }
    *(uint4*)&W2s[sn][kq * 16] = make_uint4(pk[0], pk[1], pk[2], pk[3]);
    *(uint4*)&W2s[sn][kq * 16 + 8] = make_uint4(pk[4], pk[5], pk[6], pk[7]);
  }
  for (int i = t; i < F * 64; i += 256) {
    int k = i >> 6, j = i & 63;
    W1s[k * 68 + j] = W1[i] * scale[k];
  }
  if (t < 64) {
    float acc = b1[t];
#pragma unroll
    for (int k = 0; k < F; ++k) acc += shift[k] * scale[k] * W1[k * 64 + t];
    b1s[t] = acc;
    b2s[t] = b2[t];
    bWs[t] = bW ? bW[t] : 0.f;
    bis[t] = (bi && v0 + t < n) ? bi[v0 + t] : 0.f;
  }
  for (int i = t; i < 64 * F; i += 256) {
    int r = i / F, k = i - r * F;
    int v = v0 + r;
    Xs[k * 68 + r] = (v < n) ? x[(size_t)v * F + k] : 0.f;
  }
  __syncthreads();

  int jt = t & 15;
  int vt = t >> 4;
  float c[4][4] = {};
#pragma unroll
  for (int k = 0; k < F; ++k) {
    float4 xv = *(const float4*)&Xs[k * 68 + vt * 4];
    float4 wv = *(const float4*)&W1s[k * 68 + jt * 4];
    c[0][0] += xv.x * wv.x; c[0][1] += xv.x * wv.y; c[0][2] += xv.x * wv.z; c[0][3] += xv.x * wv.w;
    c[1][0] += xv.y * wv.x; c[1][1] += xv.y * wv.y; c[1][2] += xv.y * wv.z; c[1][3] += xv.y * wv.w;
    c[2][0] += xv.z * wv.x; c[2][1] += xv.z * wv.y; c[2][2] += xv.z * wv.z; c[2][3] += xv.z * wv.w;
    c[3][0] += xv.w * wv.x; c[3][1] += xv.w * wv.y; c[3][2] += xv.w * wv.z; c[3][3] += xv.w * wv.w;
  }
#pragma unroll
  for (int i = 0; i < 4; ++i) {
    float h0 = fmaxf(c[i][0] + b1s[jt * 4 + 0], 0.f);
    float h1 = fmaxf(c[i][1] + b1s[jt * 4 + 1], 0.f);
    float h2 = fmaxf(c[i][2] + b1s[jt * 4 + 2], 0.f);
    float h3 = fmaxf(c[i][3] + b1s[jt * 4 + 3], 0.f);
    *(uint2*)&Hs[vt * 4 + i][jt * 4] = make_uint2(pack_bf2(h0, h1), pack_bf2(h2, h3));
  }
  __syncthreads();

  int l = t & 63;
  int w = t >> 6;
  int m0 = w * 16;
  int rA = m0 + (l & 15);
  int koffA = (l >> 4) * 8;
  f32x4 acc[4] = {};
  {
    bf16x8 a0 = *(const bf16x8*)&Hs[rA][koffA];
    bf16x8 a1 = *(const bf16x8*)&Hs[rA][32 + koffA];
#pragma unroll
    for (int cb = 0; cb < 4; ++cb) {
      int nB = cb * 16 + (l & 15);
      bf16x8 b0 = *(const bf16x8*)&W2s[nB][koffA];
      bf16x8 bb1 = *(const bf16x8*)&W2s[nB][32 + koffA];
      acc[cb] = __builtin_amdgcn_mfma_f32_16x16x32_bf16(a0, b0, acc[cb], 0, 0, 0);
      acc[cb] = __builtin_amdgcn_mfma_f32_16x16x32_bf16(a1, bb1, acc[cb], 0, 0, 0);
    }
  }
#pragma unroll
  for (int cb = 0; cb < 4; ++cb) {
    int colc = cb * 16 + (l & 15);
    float bias = b2s[colc];
    float bwv = bWs[colc];
#pragma unroll
    for (int j = 0; j < 4; ++j) {
      int rowc = m0 + (l >> 4) * 4 + j;
      int v = v0 + rowc;
      if (v < n) {
        float val = fmaxf(acc[cb][j] + bias, 0.f) + bis[rowc] * bwv;
        outbf[(size_t)v * 64 + colc] = f2bf(val);
      }
    }
  }
}

#define FRONT_SMEM 29824

__global__ __launch_bounds__(256) void fused_front(
    const int* __restrict__ row, const int* __restrict__ col,
    int* __restrict__ gcurV, int* __restrict__ gcurC, int* __restrict__ pairV,
    int* __restrict__ pairC, const float* __restrict__ cons_x,
    const float* __restrict__ c_sh, const float* __restrict__ c_sc,
    const float* __restrict__ cW1, const float* __restrict__ cb1,
    const float* __restrict__ cW2, const float* __restrict__ cb2,
    const float* __restrict__ var_x, const float* __restrict__ v_sh,
    const float* __restrict__ v_sc, const float* __restrict__ vW1,
    const float* __restrict__ vb1, const float* __restrict__ vW2,
    const float* __restrict__ vb2, const float* __restrict__ bi,
    const float* __restrict__ bW, u16* __restrict__ consEbf,
    u16* __restrict__ varEbf, uint2* __restrict__ padrows0,
    uint2* __restrict__ padrows1, uint2* __restrict__ padrows2) {
  __shared__ __align__(16) char smem[FRONT_SMEM];
  int b = blockIdx.x;
  if (b < NB_SCAT) {
    scatter_body(b, smem, row, col, gcurV, gcurC, pairV, pairC);
  } else if (b < NB_SCAT + NB_CONS) {
    embed_body<5>(b - NB_SCAT, smem, cons_x, c_sh, c_sc, cW1, cb1, cW2, cb2,
                  nullptr, nullptr, consEbf, N_CONS);
  } else if (b < NB_SCAT + NB_CONS + NB_VAR) {
    embed_body<19>(b - NB_SCAT - NB_CONS, smem, var_x, v_sh, v_sc, vW1, vb1,
                   vW2, vb2, bi, bW, varEbf, N_VAR);
  } else {
    int t = threadIdx.x;
    if (t < 16) padrows0[t] = make_uint2(0u, 0u);
    else if (t < 32) padrows1[t - 16] = make_uint2(0u, 0u);
    else if (t < 48) padrows2[t - 32] = make_uint2(0u, 0u);
  }
}

// ---------------- local CSR: per-bucket offsets (padded x4) + adj scatter ----------------

__global__ __launch_bounds__(1024) void local_csr(
    const int* __restrict__ pairV, const int* __restrict__ pairC,
    const int* __restrict__ gcurV, const int* __restrict__ gcurC,
    int* __restrict__ off, int* __restrict__ deg, int* __restrict__ adj) {
  __shared__ int cnt[1024];
  __shared__ int s[1024];
  __shared__ int cur[1024];
  int tid = threadIdx.x;
  int b = blockIdx.x;
  const int* pairs;
  int m, obase, nn, sh, zrow;
  int* offp;
  int* degp;
  if (b < NBV) {
    pairs = pairV + (size_t)b * CAPV;
    m = gcurV[b];
    obase = b * CAPAV;
    nn = min(1024, N_VAR - (b << 10));
    sh = VSH;
    zrow = N_CONS;
    offp = off + (b << 10);
    degp = deg + (b << 10);
  } else {
    int bb = b - NBV;
    pairs = pairC + (size_t)bb * CAPC;
    m = gcurC[bb];
    obase = NBV * CAPAV + bb * CAPAC;
    nn = min(512, N_CONS - (bb << 9));
    sh = CSH;
    zrow = N_VAR;
    offp = off + N_VAR + (bb << 9);
    degp = deg + N_VAR + (bb << 9);
  }
  int mask = (1 << sh) - 1;
  cnt[tid] = 0;
  __syncthreads();
  for (int k = tid; k < m; k += 1024) atomicAdd(&cnt[pairs[k] & mask], 1);
  __syncthreads();
  int c = cnt[tid];
  int pc = (c + 3) & ~3;
  s[tid] = pc;
  __syncthreads();
  for (int d1 = 1; d1 < 1024; d1 <<= 1) {
    int x = (tid >= d1) ? s[tid - d1] : 0;
    __syncthreads();
    s[tid] += x;
    __syncthreads();
  }
  int start = obase + s[tid] - pc;
  cur[tid] = start;
  if (tid < nn) {
    offp[tid] = start;
    degp[tid] = c;
  }
  __syncthreads();
  for (int k = tid; k < m; k += 1024) {
    int pr = pairs[k];
    int p = atomicAdd(&cur[pr & mask], 1);
    adj[p] = pr >> sh;
  }
  for (int q = c; q < pc; ++q) adj[start + q] = zrow;
}

// ---------------- Fused SAGE body (MFMA dense, padded gather, work-stealing) ----------------

template <int OUTBF>
__device__ __forceinline__ void sage_body(
    const uint2* __restrict__ srcbf, const uint2* __restrict__ dstbf,
    const int* __restrict__ off, const int* __restrict__ deg,
    const int* __restrict__ adj, const float* __restrict__ Wl,
    const float* __restrict__ bl, const float* __restrict__ Wr,
    float* __restrict__ outf, u16* __restrict__ outbf, int n, int v0,
    u16 (*Hs)[72], u16 (*Ws)[72], float* bls, int* wq) {
  int t = threadIdx.x;
  if (t < 64) bls[t] = bl[t];
  if (t == 0) *wq = 0;

  int sn = t & 63;
  int kq = t >> 6;
  {
    unsigned pk[8];
#pragma unroll
    for (int i = 0; i < 8; ++i) {
      float w0 = Wl[(size_t)(kq * 16 + 2 * i) * 64 + sn];
      float w1 = Wl[(size_t)(kq * 16 + 2 * i + 1) * 64 + sn];
      pk[i] = pack_bf2(w0, w1);
    }
    *(uint4*)&Ws[sn][kq * 16] = make_uint4(pk[0], pk[1], pk[2], pk[3]);
    *(uint4*)&Ws[sn][kq * 16 + 8] = make_uint4(pk[4], pk[5], pk[6], pk[7]);
  }
  __syncthreads();  // wq ready (Ws writes also settle before MFMA barrier later)

  // gather-mean: work-stealing over 64 rows, uniform padded 4-deep loop
  int lane = t & 15;
  while (true) {
    int r = 0;
    if (lane == 0) r = atomicAdd(wq, 1);
    r = __shfl(r, 0, 16);
    if (r >= 64) break;
    int v = v0 + r;
    float ax = 0.f, ay = 0.f, az = 0.f, aw = 0.f;
    if (v < n) {
      int s0 = off[v];
      int d = deg[v];
      int e4 = s0 + ((d + 3) & ~3);
      for (int i = s0; i < e4; i += 4) {
        int u0 = adj[i], u1 = adj[i + 1], u2 = adj[i + 2], u3 = adj[i + 3];
        uint2 a0 = srcbf[(size_t)u0 * 16 + lane];
        uint2 a1 = srcbf[(size_t)u1 * 16 + lane];
        uint2 a2 = srcbf[(size_t)u2 * 16 + lane];
        uint2 a3 = srcbf[(size_t)u3 * 16 + lane];
        ax += (b2f_lo(a0.x) + b2f_lo(a1.x)) + (b2f_lo(a2.x) + b2f_lo(a3.x));
        ay += (b2f_hi(a0.x) + b2f_hi(a1.x)) + (b2f_hi(a2.x) + b2f_hi(a3.x));
        az += (b2f_lo(a0.y) + b2f_lo(a1.y)) + (b2f_lo(a2.y) + b2f_lo(a3.y));
        aw += (b2f_hi(a0.y) + b2f_hi(a1.y)) + (b2f_hi(a2.y) + b2f_hi(a3.y));
      }
      float inv = (d > 0) ? 1.f / (float)d : 0.f;
      ax *= inv;
      ay *= inv;
      az *= inv;
      aw *= inv;
    }
    *(uint2*)&Hs[r][lane * 4] = make_uint2(pack_bf2(ax, ay), pack_bf2(az, aw));
  }
  __syncthreads();

  int l = t & 63;
  int w = t >> 6;
  int m0 = w * 16;
  int rA = m0 + (l & 15);
  int koffA = (l >> 4) * 8;
  f32x4 acc[4] = {};
  {
    bf16x8 a0 = *(const bf16x8*)&Hs[rA][koffA];
    bf16x8 a1 = *(const bf16x8*)&Hs[rA][32 + koffA];
#pragma unroll
    for (int cb = 0; cb < 4; ++cb) {
      int nB = cb * 16 + (l & 15);
      bf16x8 b0 = *(const bf16x8*)&Ws[nB][koffA];
      bf16x8 b1 = *(const bf16x8*)&Ws[nB][32 + koffA];
      acc[cb] = __builtin_amdgcn_mfma_f32_16x16x32_bf16(a0, b0, acc[cb], 0, 0, 0);
      acc[cb] = __builtin_amdgcn_mfma_f32_16x16x32_bf16(a1, b1, acc[cb], 0, 0, 0);
    }
  }
  __syncthreads();

#pragma unroll
  for (int r4 = 0; r4 < 4; ++r4) {
    int idx = t + 256 * r4;
    int rowi = idx >> 4, f4 = idx & 15;
    int v = v0 + rowi;
    uint2 val = (v < n) ? dstbf[(size_t)v * 16 + f4] : make_uint2(0u, 0u);
    *(uint2*)&Hs[rowi][f4 * 4] = val;
  }
  {
    unsigned pk[8];
#pragma unroll
    for (int i = 0; i < 8; ++i) {
      float w0 = Wr[(size_t)(kq * 16 + 2 * i) * 64 + sn];
      float w1 = Wr[(size_t)(kq * 16 + 2 * i + 1) * 64 + sn];
      pk[i] = pack_bf2(w0, w1);
    }
    *(uint4*)&Ws[sn][kq * 16] = make_uint4(pk[0], pk[1], pk[2], pk[3]);
    *(uint4*)&Ws[sn][kq * 16 + 8] = make_uint4(pk[4], pk[5], pk[6], pk[7]);
  }
  __syncthreads();

  {
    bf16x8 a0 = *(const bf16x8*)&Hs[rA][koffA];
    bf16x8 a1 = *(const bf16x8*)&Hs[rA][32 + koffA];
#pragma unroll
    for (int cb = 0; cb < 4; ++cb) {
      int nB = cb * 16 + (l & 15);
      bf16x8 b0 = *(const bf16x8*)&Ws[nB][koffA];
      bf16x8 b1 = *(const bf16x8*)&Ws[nB][32 + koffA];
      acc[cb] = __builtin_amdgcn_mfma_f32_16x16x32_bf16(a0, b0, acc[cb], 0, 0, 0);
      acc[cb] = __builtin_amdgcn_mfma_f32_16x16x32_bf16(a1, b1, acc[cb], 0, 0, 0);
    }
  }

#pragma unroll
  for (int cb = 0; cb < 4; ++cb) {
    int colc = cb * 16 + (l & 15);
    float bias = bls[colc];
#pragma unroll
    for (int j = 0; j < 4; ++j) {
      int rowc = m0 + (l >> 4) * 4 + j;
      int v = v0 + rowc;
      if (v < n) {
        float val = fmaxf(acc[cb][j] + bias, 0.f);
        if (OUTBF) {
          outbf[(size_t)v * 64 + colc] = f2bf(val);
        } else {
          outf[(size_t)v * 64 + colc] = val;
        }
      }
    }
  }
}

// layer 0: both directions in one dispatch
__global__ __launch_bounds__(256) void sage_l0(
    const uint2* __restrict__ consEbf, const uint2* __restrict__ varEbf,
    const int* __restrict__ off, const int* __restrict__ deg,
    const int* __restrict__ adj, const float* __restrict__ Wl_cv,
    const float* __restrict__ bl_cv, const float* __restrict__ Wr_cv,
    const float* __restrict__ Wl_vc, const float* __restrict__ bl_vc,
    const float* __restrict__ Wr_vc, u16* __restrict__ var1bf,
    u16* __restrict__ cons1bf) {
  __shared__ u16 Hs[64][72];
  __shared__ u16 Ws[64][72];
  __shared__ float bls[64];
  __shared__ int wq;
  int b = blockIdx.x;
  if (b < NB_VAR) {
    sage_body<1>(consEbf, varEbf, off, deg, adj, Wl_cv, bl_cv, Wr_cv, nullptr,
                 var1bf, N_VAR, b * 64, Hs, Ws, bls, &wq);
  } else {
    sage_body<1>(varEbf, consEbf, off + N_VAR, deg + N_VAR, adj, Wl_vc, bl_vc,
                 Wr_vc, nullptr, cons1bf, N_CONS, (b - NB_VAR) * 64, Hs, Ws,
                 bls, &wq);
  }
}

// layer 1: var side only, fp32 out
__global__ __launch_bounds__(256) void sage_l1(
    const uint2* __restrict__ cons1bf, const uint2* __restrict__ var1bf,
    const int* __restrict__ off, const int* __restrict__ deg,
    const int* __restrict__ adj, const float* __restrict__ Wl,
    const float* __restrict__ bl, const float* __restrict__ Wr,
    float* __restrict__ out) {
  __shared__ u16 Hs[64][72];
  __shared__ u16 Ws[64][72];
  __shared__ float bls[64];
  __shared__ int wq;
  sage_body<0>(cons1bf, var1bf, off, deg, adj, Wl, bl, Wr, out, nullptr, N_VAR,
               blockIdx.x * 64, Hs, Ws, bls, &wq);
}

// ---------------- host ----------------

extern "C" void kernel_launch(void* const* d_in, const int* in_sizes, int n_in,
                              void* d_out, int out_size, void* d_ws, size_t ws_size,
                              hipStream_t stream) {
  const float* cons_x = (const float*)d_in[0];
  const float* var_x  = (const float*)d_in[1];
  const int*   eidx   = (const int*)d_in[2];
  const float* bi     = (const float*)d_in[4];
  const float* c_sh   = (const float*)d_in[5];
  const float* c_sc   = (const float*)d_in[6];
  const float* v_sh   = (const float*)d_in[7];
  const float* v_sc   = (const float*)d_in[8];
  const float* cW1 = (const float*)d_in[11];
  const float* cb1 = (const float*)d_in[12];
  const float* cW2 = (const float*)d_in[13];
  const float* cb2 = (const float*)d_in[14];
  const float* vW1 = (const float*)d_in[15];
  const float* vb1 = (const float*)d_in[16];
  const float* vW2 = (const float*)d_in[17];
  const float* vb2 = (const float*)d_in[18];
  const float* bW  = (const float*)d_in[19];
  const float* Wl_cv = (const float*)d_in[20];
  const float* bl_cv = (const float*)d_in[21];
  const float* Wr_cv = (const float*)d_in[22];
  const float* Wl_vc = (const float*)d_in[23];
  const float* bl_vc = (const float*)d_in[24];
  const float* Wr_vc = (const float*)d_in[25];

  const int* row = eidx;           // [E] constraint index per edge
  const int* col = eidx + N_EDGE;  // [E] variable index per edge

  char* ws = (char*)d_ws;
  size_t o = 0;
  auto alloc = [&](size_t bytes) {
    char* p = ws + o;
    o = (o + bytes + 255) & ~(size_t)255;
    return p;
  };
  int* off   = (int*)alloc((size_t)N_TOT * sizeof(int));
  int* deg   = (int*)alloc((size_t)N_TOT * sizeof(int));
  int* adj   = (int*)alloc(((size_t)NBV * CAPAV + (size_t)NBC * CAPAC) * sizeof(int));
  int* pairV = (int*)alloc((size_t)NBV * CAPV * sizeof(int));
  int* pairC = (int*)alloc((size_t)NBC * CAPC * sizeof(int));
  int* gcurV = (int*)alloc(256 * sizeof(int));
  int* gcurC = (int*)alloc(256 * sizeof(int));
  uint2* consEbf = (uint2*)alloc((size_t)(N_CONS + 1) * EMB * 2);
  uint2* varEbf  = (uint2*)alloc((size_t)(N_VAR + 1) * EMB * 2);
  uint2* cons1bf = (uint2*)alloc((size_t)(N_CONS + 1) * EMB * 2);
  uint2* var1bf  = (uint2*)alloc((size_t)N_VAR * EMB * 2);
  float* var_out = (float*)d_out;

  // bucket counters -> 0 (gcurV/gcurC are contiguous allocations)
  hipMemsetAsync(gcurV, 0, 2048, stream);

  fused_front<<<NB_SCAT + NB_CONS + NB_VAR + 1, 256, 0, stream>>>(
      row, col, gcurV, gcurC, pairV, pairC, cons_x, c_sh, c_sc, cW1, cb1, cW2,
      cb2, var_x, v_sh, v_sc, vW1, vb1, vW2, vb2, bi, bW, (u16*)consEbf,
      (u16*)varEbf, consEbf + (size_t)N_CONS * 16, varEbf + (size_t)N_VAR * 16,
      cons1bf + (size_t)N_CONS * 16);

  local_csr<<<NBV + NBC, 1024, 0, stream>>>(pairV, pairC, gcurV, gcurC, off,
                                            deg, adj);

  sage_l0<<<NB_VAR + NB_CONS, 256, 0, stream>>>(
      consEbf, varEbf, off, deg, adj, Wl_cv, bl_cv, Wr_cv, Wl_vc, bl_vc, Wr_vc,
      (u16*)var1bf, (u16*)cons1bf);
  sage_l1<<<NB_VAR, 256, 0, stream>>>(cons1bf, var1bf, off, deg, adj,
                                      Wl_cv + 4096, bl_cv + 64, Wr_cv + 4096,
                                      var_out);
}